// Round 4
// baseline (1390.939 us; speedup 1.0000x reference)
//
#include <hip/hip_runtime.h>

#define HD 32   // hidden/emb dim
#define ND 16   // node feature dim
#define ED 8    // edge feature dim

// ===========================================================================
// CSR build: histogram -> parallel 3-pass exclusive scan -> scatter
// ===========================================================================
__global__ __launch_bounds__(256) void hist_kernel(
    const int* __restrict__ keys, int* __restrict__ deg, int n)
{
    int i = blockIdx.x * 256 + threadIdx.x;
    if (i < n) atomicAdd(&deg[keys[i]], 1);
}

__global__ __launch_bounds__(256) void hist2_kernel(
    const int* __restrict__ k1, int* __restrict__ d1,
    const int* __restrict__ k2, int* __restrict__ d2, int n)
{
    int i = blockIdx.x * 256 + threadIdx.x;
    if (i < n) { atomicAdd(&d1[k1[i]], 1); atomicAdd(&d2[k2[i]], 1); }
}

// pass 1: per-1024-chunk sums
__global__ __launch_bounds__(256) void scan_p1(
    const int* __restrict__ in, int* __restrict__ csum, int n)
{
    int c = blockIdx.x;
    int i0 = c * 1024 + threadIdx.x * 4;
    int s = 0;
#pragma unroll
    for (int j = 0; j < 4; j++) { int i = i0 + j; if (i < n) s += in[i]; }
#pragma unroll
    for (int m = 1; m < 64; m <<= 1) s += __shfl_xor(s, m, 64);
    __shared__ int ws[4];
    if ((threadIdx.x & 63) == 0) ws[threadIdx.x >> 6] = s;
    __syncthreads();
    if (threadIdx.x == 0) csum[c] = ws[0] + ws[1] + ws[2] + ws[3];
}

// pass 2: exclusive scan of chunk sums in place (n <= 1024), 3 arrays
__device__ __forceinline__ void exscan_block(int* __restrict__ c, int n)
{
    int i = threadIdx.x;
    int v = (i < n) ? c[i] : 0;
    int x = v;
    int lane = i & 63, wid = i >> 6;
#pragma unroll
    for (int dd = 1; dd < 64; dd <<= 1) {
        int y = __shfl_up(x, dd, 64);
        if (lane >= dd) x += y;
    }
    __shared__ int ws[16];
    if (lane == 63) ws[wid] = x;
    __syncthreads();
    if (i == 0) {
        int a = 0;
#pragma unroll
        for (int w = 0; w < 16; w++) { int t = ws[w]; ws[w] = a; a += t; }
    }
    __syncthreads();
    int excl = ws[wid] + x - v;
    if (i < n) c[i] = excl;
}

__global__ __launch_bounds__(1024) void scan_p2(
    int* c0, int n0, int* c1, int n1, int* c2, int n2)
{
    if (blockIdx.x == 0)      exscan_block(c0, n0);
    else if (blockIdx.x == 1) exscan_block(c1, n1);
    else                      exscan_block(c2, n2);
}

// pass 3: per-chunk exclusive prefix + chunk base -> off, cur
__global__ __launch_bounds__(1024) void scan_p3(
    const int* __restrict__ deg, const int* __restrict__ cbase,
    int* __restrict__ off, int* __restrict__ cur, int n)
{
    int c = blockIdx.x;
    int i = c * 1024 + threadIdx.x;
    int v = (i < n) ? deg[i] : 0;
    int x = v;
    int lane = threadIdx.x & 63, wid = threadIdx.x >> 6;
#pragma unroll
    for (int dd = 1; dd < 64; dd <<= 1) {
        int y = __shfl_up(x, dd, 64);
        if (lane >= dd) x += y;
    }
    __shared__ int ws[16];
    if (lane == 63) ws[wid] = x;
    __syncthreads();
    if (threadIdx.x == 0) {
        int a = 0;
#pragma unroll
        for (int w = 0; w < 16; w++) { int t = ws[w]; ws[w] = a; a += t; }
    }
    __syncthreads();
    int excl = cbase[c] + ws[wid] + x - v;
    if (i < n) { off[i] = excl; cur[i] = excl; }
}

__global__ __launch_bounds__(256) void scatter_kernel(
    const int* __restrict__ keys, int* __restrict__ cur,
    int* __restrict__ csr, int n)
{
    int i = blockIdx.x * 256 + threadIdx.x;
    if (i < n) { int p = atomicAdd(&cur[keys[i]], 1); csr[p] = i; }
}

__global__ __launch_bounds__(256) void scatter2_kernel(
    const int* __restrict__ k1, int* __restrict__ cur1, int* __restrict__ csr1,
    const int* __restrict__ k2, int* __restrict__ cur2, int* __restrict__ csr2, int n)
{
    int i = blockIdx.x * 256 + threadIdx.x;
    if (i < n) {
        int p = atomicAdd(&cur1[k1[i]], 1); csr1[p] = i;
        int q = atomicAdd(&cur2[k2[i]], 1); csr2[q] = i;
    }
}

// ===========================================================================
// Precompute folded layer-2 matrices (layer2 of edge MLPs folded into the
// next MLP's layer1): Mg = gvW2 @ fvW1[16:48], bg = gvb2 @ fvW1[16:48], etc.
// ===========================================================================
__global__ __launch_bounds__(256) void precomp_kernel(
    const float* __restrict__ gvW2, const float* __restrict__ gvb2,
    const float* __restrict__ hvW2, const float* __restrict__ hvb2,
    const float* __restrict__ gaW2, const float* __restrict__ gab2,
    const float* __restrict__ fvW1, const float* __restrict__ faW1,
    float* __restrict__ Mg, float* __restrict__ bg,
    float* __restrict__ Mh, float* __restrict__ bh,
    float* __restrict__ Mga, float* __restrict__ bga)
{
    int t = threadIdx.x;
    for (int idx = t; idx < HD * HD; idx += 256) {
        int c = idx >> 5, h = idx & 31;
        float sg = 0.f, sh = 0.f, sa = 0.f;
#pragma unroll
        for (int o = 0; o < HD; o++) {
            sg = fmaf(gvW2[c * HD + o], fvW1[(ND + o) * HD + h], sg);
            sh = fmaf(hvW2[c * HD + o], fvW1[(ND + HD + o) * HD + h], sh);
            sa = fmaf(gaW2[c * HD + o], faW1[(ND + o) * HD + h], sa);
        }
        Mg[idx] = sg; Mh[idx] = sh; Mga[idx] = sa;
    }
    if (t < HD) {
        float sg = 0.f, sh = 0.f, sa = 0.f;
#pragma unroll
        for (int o = 0; o < HD; o++) {
            sg = fmaf(gvb2[o], fvW1[(ND + o) * HD + t], sg);
            sh = fmaf(hvb2[o], fvW1[(ND + HD + o) * HD + t], sh);
            sa = fmaf(gab2[o], faW1[(ND + o) * HD + t], sa);
        }
        bg[t] = sg; bh[t] = sh; bga[t] = sa;
    }
}

// ===========================================================================
// fv edge kernel, CHANNEL-MAJOR: 32 lanes per variable node, lane = channel.
// Lane keeps its W1 column (40 floats) in registers; px = b1 + xv.W1[:,ch]
// hoisted once; per edge only 24 FMA; acc is a single register; no reduce.
// ===========================================================================
__global__ __launch_bounds__(256) void fv_edge_kernel(
    const float* __restrict__ xv, const float* __restrict__ xc,
    const float* __restrict__ xa,
    const int* __restrict__ c2v_src, const int* __restrict__ a2v_src,
    const float* __restrict__ ea_c, const float* __restrict__ ea_a,
    const int* __restrict__ off_g, const int* __restrict__ deg_g, const int* __restrict__ csr_g,
    const int* __restrict__ off_h, const int* __restrict__ deg_h, const int* __restrict__ csr_h,
    const float* __restrict__ gvW1, const float* __restrict__ gvb1,
    const float* __restrict__ hvW1, const float* __restrict__ hvb1,
    float* __restrict__ Ag, float* __restrict__ Ah, int nV)
{
    int gid = blockIdx.x * 256 + threadIdx.x;
    int v   = gid >> 5;
    int ch  = threadIdx.x & 31;
    if (v >= nV) return;

    float xvr[ND];
    {
        const float4* p = reinterpret_cast<const float4*>(xv + (size_t)v * ND);
#pragma unroll
        for (int q = 0; q < 4; q++) {
            float4 t = p[q];
            xvr[4*q+0] = t.x; xvr[4*q+1] = t.y; xvr[4*q+2] = t.z; xvr[4*q+3] = t.w;
        }
    }

    // ---------------- g: c2v edges ----------------
    {
        float w[40];
#pragma unroll
        for (int i = 0; i < 40; i++) w[i] = gvW1[i * HD + ch];
        float px = gvb1[ch];
#pragma unroll
        for (int i = 0; i < ND; i++) px = fmaf(xvr[i], w[i], px);

        float acc = 0.f;
        int base = off_g[v], d = deg_g[v];
        for (int k = 0; k < d; k++) {
            int e = csr_g[base + k];
            int s = c2v_src[e];
            const float4* p = reinterpret_cast<const float4*>(xc + (size_t)s * ND);
            float4 a0 = p[0], a1 = p[1], a2 = p[2], a3 = p[3];
            const float4* pe = reinterpret_cast<const float4*>(ea_c + (size_t)e * ED);
            float4 e0 = pe[0], e1 = pe[1];
            float t0 = px, t1 = 0.f;
            t0 = fmaf(a0.x, w[16], t0); t1 = fmaf(a0.y, w[17], t1);
            t0 = fmaf(a0.z, w[18], t0); t1 = fmaf(a0.w, w[19], t1);
            t0 = fmaf(a1.x, w[20], t0); t1 = fmaf(a1.y, w[21], t1);
            t0 = fmaf(a1.z, w[22], t0); t1 = fmaf(a1.w, w[23], t1);
            t0 = fmaf(a2.x, w[24], t0); t1 = fmaf(a2.y, w[25], t1);
            t0 = fmaf(a2.z, w[26], t0); t1 = fmaf(a2.w, w[27], t1);
            t0 = fmaf(a3.x, w[28], t0); t1 = fmaf(a3.y, w[29], t1);
            t0 = fmaf(a3.z, w[30], t0); t1 = fmaf(a3.w, w[31], t1);
            t0 = fmaf(e0.x, w[32], t0); t1 = fmaf(e0.y, w[33], t1);
            t0 = fmaf(e0.z, w[34], t0); t1 = fmaf(e0.w, w[35], t1);
            t0 = fmaf(e1.x, w[36], t0); t1 = fmaf(e1.y, w[37], t1);
            t0 = fmaf(e1.z, w[38], t0); t1 = fmaf(e1.w, w[39], t1);
            acc += fmaxf(t0 + t1, 0.f);
        }
        Ag[(size_t)v * HD + ch] = acc;
    }

    // ---------------- h: a2v edges ----------------
    {
        float w[40];
#pragma unroll
        for (int i = 0; i < 40; i++) w[i] = hvW1[i * HD + ch];
        float px = hvb1[ch];
#pragma unroll
        for (int i = 0; i < ND; i++) px = fmaf(xvr[i], w[i], px);

        float acc = 0.f;
        int base = off_h[v], d = deg_h[v];
        for (int k = 0; k < d; k++) {
            int e = csr_h[base + k];
            int s = a2v_src[e];
            const float4* p = reinterpret_cast<const float4*>(xa + (size_t)s * ND);
            float4 a0 = p[0], a1 = p[1], a2 = p[2], a3 = p[3];
            const float4* pe = reinterpret_cast<const float4*>(ea_a + (size_t)e * ED);
            float4 e0 = pe[0], e1 = pe[1];
            float t0 = px, t1 = 0.f;
            t0 = fmaf(a0.x, w[16], t0); t1 = fmaf(a0.y, w[17], t1);
            t0 = fmaf(a0.z, w[18], t0); t1 = fmaf(a0.w, w[19], t1);
            t0 = fmaf(a1.x, w[20], t0); t1 = fmaf(a1.y, w[21], t1);
            t0 = fmaf(a1.z, w[22], t0); t1 = fmaf(a1.w, w[23], t1);
            t0 = fmaf(a2.x, w[24], t0); t1 = fmaf(a2.y, w[25], t1);
            t0 = fmaf(a2.z, w[26], t0); t1 = fmaf(a2.w, w[27], t1);
            t0 = fmaf(a3.x, w[28], t0); t1 = fmaf(a3.y, w[29], t1);
            t0 = fmaf(a3.z, w[30], t0); t1 = fmaf(a3.w, w[31], t1);
            t0 = fmaf(e0.x, w[32], t0); t1 = fmaf(e0.y, w[33], t1);
            t0 = fmaf(e0.z, w[34], t0); t1 = fmaf(e0.w, w[35], t1);
            t0 = fmaf(e1.x, w[36], t0); t1 = fmaf(e1.y, w[37], t1);
            t0 = fmaf(e1.z, w[38], t0); t1 = fmaf(e1.w, w[39], t1);
            acc += fmaxf(t0 + t1, 0.f);
        }
        Ah[(size_t)v * HD + ch] = acc;
    }
}

// ===========================================================================
// fv node kernel: one thread per v (folded layer-2 via Mg/Mh).
// ===========================================================================
__global__ __launch_bounds__(256) void fv_node_kernel(
    const float* __restrict__ xv,
    const float* __restrict__ Ag, const float* __restrict__ Ah,
    const int* __restrict__ deg_g, const int* __restrict__ deg_h,
    const float* __restrict__ fvW1, const float* __restrict__ fvb1,
    const float* __restrict__ fvW2, const float* __restrict__ fvb2,
    const float* __restrict__ Mg, const float* __restrict__ bg,
    const float* __restrict__ Mh, const float* __restrict__ bh,
    float* __restrict__ fv, int nV)
{
    int v = blockIdx.x * 256 + threadIdx.x;
    if (v >= nV) return;

    float xvr[ND], agr[HD], ahr[HD];
    {
        const float4* p = reinterpret_cast<const float4*>(xv + (size_t)v * ND);
#pragma unroll
        for (int q = 0; q < 4; q++) {
            float4 t = p[q];
            xvr[4*q+0] = t.x; xvr[4*q+1] = t.y; xvr[4*q+2] = t.z; xvr[4*q+3] = t.w;
        }
        const float4* pg = reinterpret_cast<const float4*>(Ag + (size_t)v * HD);
        const float4* ph = reinterpret_cast<const float4*>(Ah + (size_t)v * HD);
#pragma unroll
        for (int q = 0; q < 8; q++) {
            float4 t = pg[q];
            agr[4*q+0] = t.x; agr[4*q+1] = t.y; agr[4*q+2] = t.z; agr[4*q+3] = t.w;
            float4 u = ph[q];
            ahr[4*q+0] = u.x; ahr[4*q+1] = u.y; ahr[4*q+2] = u.z; ahr[4*q+3] = u.w;
        }
    }
    int dg = deg_g[v], dh = deg_h[v];
    float invg = dg > 0 ? 1.f / (float)dg : 0.f;
    float invh = dh > 0 ? 1.f / (float)dh : 0.f;
    float bgk  = dg > 0 ? 1.f : 0.f;
    float bhk  = dh > 0 ? 1.f : 0.f;

    float hid[HD];
#pragma unroll
    for (int h = 0; h < HD; h++) {
        float t = fvb1[h] + bgk * bg[h] + bhk * bh[h];
#pragma unroll
        for (int i = 0; i < ND; i++) t = fmaf(xvr[i], fvW1[i * HD + h], t);
        float sg = 0.f, sh = 0.f;
#pragma unroll
        for (int c = 0; c < HD; c++) {
            sg = fmaf(agr[c], Mg[c * HD + h], sg);
            sh = fmaf(ahr[c], Mh[c * HD + h], sh);
        }
        t += invg * sg + invh * sh;
        hid[h] = fmaxf(t, 0.f);
    }
    float* ob = fv + (size_t)v * HD;
#pragma unroll
    for (int o = 0; o < HD; o++) {
        float t = fvb2[o];
#pragma unroll
        for (int h = 0; h < HD; h++) t = fmaf(hid[h], fvW2[h * HD + o], t);
        ob[o] = t;
    }
}

// ===========================================================================
// ga edge kernel, CHANNEL-MAJOR: one wave per cut node; lane = ch + 32*half.
// W1 column (40: fv rows + ea rows) register-resident; xa.W1 hoisted as px.
// Halves process alternating edges; one shfl_xor(32) combines.
// ===========================================================================
__global__ __launch_bounds__(256) void ga_edge_kernel(
    const float* __restrict__ xa, const float* __restrict__ fvv,
    const float* __restrict__ ea_a,
    const int* __restrict__ a2v_tgt,
    const int* __restrict__ off_a, const int* __restrict__ deg_a, const int* __restrict__ csr_a,
    const float* __restrict__ gaW1, const float* __restrict__ gab1,
    float* __restrict__ Aga, int nA)
{
    int gid  = blockIdx.x * 256 + threadIdx.x;
    int a    = gid >> 6;
    int lane = threadIdx.x & 63;
    int ch   = lane & 31;
    int half = lane >> 5;
    if (a >= nA) return;

    float px = gab1[ch];
    {
        const float4* p = reinterpret_cast<const float4*>(xa + (size_t)a * ND);
#pragma unroll
        for (int q = 0; q < 4; q++) {
            float4 t = p[q];
            px = fmaf(t.x, gaW1[(4*q+0) * HD + ch], px);
            px = fmaf(t.y, gaW1[(4*q+1) * HD + ch], px);
            px = fmaf(t.z, gaW1[(4*q+2) * HD + ch], px);
            px = fmaf(t.w, gaW1[(4*q+3) * HD + ch], px);
        }
    }
    float w[40];
#pragma unroll
    for (int i = 0; i < 40; i++) w[i] = gaW1[(ND + i) * HD + ch];

    float acc = 0.f;
    int base = off_a[a], d = deg_a[a];
    for (int k = half; k < d; k += 2) {
        int e = csr_a[base + k];
        int t = a2v_tgt[e];
        const float4* p = reinterpret_cast<const float4*>(fvv + (size_t)t * HD);
        float4 f0 = p[0], f1 = p[1], f2 = p[2], f3 = p[3];
        float4 f4 = p[4], f5 = p[5], f6 = p[6], f7 = p[7];
        const float4* pe = reinterpret_cast<const float4*>(ea_a + (size_t)e * ED);
        float4 e0 = pe[0], e1 = pe[1];
        float t0 = px, t1 = 0.f;
        t0 = fmaf(f0.x, w[ 0], t0); t1 = fmaf(f0.y, w[ 1], t1);
        t0 = fmaf(f0.z, w[ 2], t0); t1 = fmaf(f0.w, w[ 3], t1);
        t0 = fmaf(f1.x, w[ 4], t0); t1 = fmaf(f1.y, w[ 5], t1);
        t0 = fmaf(f1.z, w[ 6], t0); t1 = fmaf(f1.w, w[ 7], t1);
        t0 = fmaf(f2.x, w[ 8], t0); t1 = fmaf(f2.y, w[ 9], t1);
        t0 = fmaf(f2.z, w[10], t0); t1 = fmaf(f2.w, w[11], t1);
        t0 = fmaf(f3.x, w[12], t0); t1 = fmaf(f3.y, w[13], t1);
        t0 = fmaf(f3.z, w[14], t0); t1 = fmaf(f3.w, w[15], t1);
        t0 = fmaf(f4.x, w[16], t0); t1 = fmaf(f4.y, w[17], t1);
        t0 = fmaf(f4.z, w[18], t0); t1 = fmaf(f4.w, w[19], t1);
        t0 = fmaf(f5.x, w[20], t0); t1 = fmaf(f5.y, w[21], t1);
        t0 = fmaf(f5.z, w[22], t0); t1 = fmaf(f5.w, w[23], t1);
        t0 = fmaf(f6.x, w[24], t0); t1 = fmaf(f6.y, w[25], t1);
        t0 = fmaf(f6.z, w[26], t0); t1 = fmaf(f6.w, w[27], t1);
        t0 = fmaf(f7.x, w[28], t0); t1 = fmaf(f7.y, w[29], t1);
        t0 = fmaf(f7.z, w[30], t0); t1 = fmaf(f7.w, w[31], t1);
        t0 = fmaf(e0.x, w[32], t0); t1 = fmaf(e0.y, w[33], t1);
        t0 = fmaf(e0.z, w[34], t0); t1 = fmaf(e0.w, w[35], t1);
        t0 = fmaf(e1.x, w[36], t0); t1 = fmaf(e1.y, w[37], t1);
        t0 = fmaf(e1.z, w[38], t0); t1 = fmaf(e1.w, w[39], t1);
        acc += fmaxf(t0 + t1, 0.f);
    }
    acc += __shfl_xor(acc, 32, 64);
    if (half == 0) Aga[(size_t)a * HD + ch] = acc;
}

// ===========================================================================
// fa node kernel: one thread per a node -> final output.
// ===========================================================================
__global__ __launch_bounds__(256) void fa_node_kernel(
    const float* __restrict__ xa,
    const float* __restrict__ Aga, const int* __restrict__ deg_a,
    const float* __restrict__ faW1, const float* __restrict__ fab1,
    const float* __restrict__ faW2, const float* __restrict__ fab2,
    const float* __restrict__ Mga, const float* __restrict__ bga,
    float* __restrict__ out, int nA)
{
    int a = blockIdx.x * 256 + threadIdx.x;
    if (a >= nA) return;

    float xar[ND], agr[HD];
    {
        const float4* p = reinterpret_cast<const float4*>(xa + (size_t)a * ND);
#pragma unroll
        for (int q = 0; q < 4; q++) {
            float4 t = p[q];
            xar[4*q+0] = t.x; xar[4*q+1] = t.y; xar[4*q+2] = t.z; xar[4*q+3] = t.w;
        }
        const float4* pg = reinterpret_cast<const float4*>(Aga + (size_t)a * HD);
#pragma unroll
        for (int q = 0; q < 8; q++) {
            float4 t = pg[q];
            agr[4*q+0] = t.x; agr[4*q+1] = t.y; agr[4*q+2] = t.z; agr[4*q+3] = t.w;
        }
    }
    int d = deg_a[a];
    float inv = d > 0 ? 1.f / (float)d : 0.f;
    float bk  = d > 0 ? 1.f : 0.f;

    float hid[HD];
#pragma unroll
    for (int h = 0; h < HD; h++) {
        float t = fab1[h] + bk * bga[h];
#pragma unroll
        for (int i = 0; i < ND; i++) t = fmaf(xar[i], faW1[i * HD + h], t);
        float s = 0.f;
#pragma unroll
        for (int c = 0; c < HD; c++) s = fmaf(agr[c], Mga[c * HD + h], s);
        t += inv * s;
        hid[h] = fmaxf(t, 0.f);
    }
    float* ob = out + (size_t)a * HD;
#pragma unroll
    for (int o = 0; o < HD; o++) {
        float t = fab2[o];
#pragma unroll
        for (int h = 0; h < HD; h++) t = fmaf(hid[h], faW2[h * HD + o], t);
        ob[o] = t;
    }
}

// ===========================================================================
extern "C" void kernel_launch(void* const* d_in, const int* in_sizes, int n_in,
                              void* d_out, int out_size, void* d_ws, size_t ws_size,
                              hipStream_t stream) {
    const float* x_c    = (const float*)d_in[0];
    const float* x_v    = (const float*)d_in[1];
    const float* x_a    = (const float*)d_in[2];
    const int*   ei_c2v = (const int*)d_in[3];
    const int*   ei_a2v = (const int*)d_in[4];
    const float* ea_c2v = (const float*)d_in[5];
    const float* ea_a2v = (const float*)d_in[6];
    const float *gv_W1=(const float*)d_in[7],  *gv_b1=(const float*)d_in[8],
                *gv_W2=(const float*)d_in[9],  *gv_b2=(const float*)d_in[10];
    const float *hv_W1=(const float*)d_in[11], *hv_b1=(const float*)d_in[12],
                *hv_W2=(const float*)d_in[13], *hv_b2=(const float*)d_in[14];
    const float *fv_W1=(const float*)d_in[15], *fv_b1=(const float*)d_in[16],
                *fv_W2=(const float*)d_in[17], *fv_b2=(const float*)d_in[18];
    const float *ga_W1=(const float*)d_in[19], *ga_b1=(const float*)d_in[20],
                *ga_W2=(const float*)d_in[21], *ga_b2=(const float*)d_in[22];
    const float *fa_W1=(const float*)d_in[23], *fa_b1=(const float*)d_in[24],
                *fa_W2=(const float*)d_in[25], *fa_b2=(const float*)d_in[26];

    const int NV = in_sizes[1] / ND;
    const int NA = in_sizes[2] / ND;
    const int EC = in_sizes[3] / 2;
    const int EA = in_sizes[4] / 2;
    (void)n_in; (void)ws_size; (void)out_size;

    const int* c2v_s = ei_c2v;            // constraint side of c2v
    const int* c2v_t = ei_c2v + EC;       // variable side
    const int* a2v_s = ei_a2v;            // cut node side
    const int* a2v_t = ei_a2v + EA;       // variable side

    const int chunksV = (NV + 1023) / 1024;
    const int chunksA = (NA + 1023) / 1024;

    // Workspace layout (4B words)
    int* wsI = (int*)d_ws;
    int* deg_g = wsI;                 // NV
    int* deg_h = deg_g + NV;          // NV
    int* deg_a = deg_h + NV;          // NA
    int* off_g = deg_a + NA;          // NV
    int* off_h = off_g + NV;          // NV
    int* off_a = off_h + NV;          // NA
    int* cur_g = off_a + NA;          // NV
    int* cur_h = cur_g + NV;          // NV
    int* cur_a = cur_h + NV;          // NA
    int* csum_g = cur_a + NA;         // 1024
    int* csum_h = csum_g + 1024;      // 1024
    int* csum_a = csum_h + 1024;      // 1024
    int* csr_g = csum_a + 1024;       // EC
    int* csr_h = csr_g + EC;          // EA
    int* csr_a = csr_h + EA;          // EA
    float* Ag  = (float*)(csr_a + EA);   // NV*HD
    float* Ah  = Ag + (size_t)NV * HD;   // NV*HD
    float* Aga = Ah + (size_t)NV * HD;   // NA*HD
    float* f_v = Aga + (size_t)NA * HD;  // NV*HD
    float* Mg  = f_v + (size_t)NV * HD;  // 1024
    float* Mh  = Mg + HD * HD;           // 1024
    float* Mga = Mh + HD * HD;           // 1024
    float* bgv = Mga + HD * HD;          // 32
    float* bhv = bgv + HD;               // 32
    float* bgav= bhv + HD;               // 32

    // zero degree histograms only
    hipMemsetAsync(deg_g, 0, (size_t)(2 * NV + NA) * sizeof(int), stream);

    // folded layer-2 matrices (independent of CSR)
    precomp_kernel<<<1, 256, 0, stream>>>(gv_W2, gv_b2, hv_W2, hv_b2, ga_W2, ga_b2,
                                          fv_W1, fa_W1, Mg, bgv, Mh, bhv, Mga, bgav);

    // histograms
    hist_kernel<<<(EC + 255) / 256, 256, 0, stream>>>(c2v_t, deg_g, EC);
    hist2_kernel<<<(EA + 255) / 256, 256, 0, stream>>>(a2v_t, deg_h, a2v_s, deg_a, EA);

    // parallel exclusive scans
    scan_p1<<<chunksV, 256, 0, stream>>>(deg_g, csum_g, NV);
    scan_p1<<<chunksV, 256, 0, stream>>>(deg_h, csum_h, NV);
    scan_p1<<<chunksA, 256, 0, stream>>>(deg_a, csum_a, NA);
    scan_p2<<<3, 1024, 0, stream>>>(csum_g, chunksV, csum_h, chunksV, csum_a, chunksA);
    scan_p3<<<chunksV, 1024, 0, stream>>>(deg_g, csum_g, off_g, cur_g, NV);
    scan_p3<<<chunksV, 1024, 0, stream>>>(deg_h, csum_h, off_h, cur_h, NV);
    scan_p3<<<chunksA, 1024, 0, stream>>>(deg_a, csum_a, off_a, cur_a, NA);

    // scatter edge ids into CSR
    scatter_kernel<<<(EC + 255) / 256, 256, 0, stream>>>(c2v_t, cur_g, csr_g, EC);
    scatter2_kernel<<<(EA + 255) / 256, 256, 0, stream>>>(a2v_t, cur_h, csr_h,
                                                          a2v_s, cur_a, csr_a, EA);

    // variable-node edge aggregation (channel-major, 32 lanes/node)
    fv_edge_kernel<<<(NV * 32 + 255) / 256, 256, 0, stream>>>(
        x_v, x_c, x_a, c2v_s, a2v_s, ea_c2v, ea_a2v,
        off_g, deg_g, csr_g, off_h, deg_h, csr_h,
        gv_W1, gv_b1, hv_W1, hv_b1, Ag, Ah, NV);

    // variable-node MLP -> f_v
    fv_node_kernel<<<(NV + 255) / 256, 256, 0, stream>>>(
        x_v, Ag, Ah, deg_g, deg_h,
        fv_W1, fv_b1, fv_W2, fv_b2, Mg, bgv, Mh, bhv, f_v, NV);

    // cut-node edge aggregation (channel-major, 64 lanes/node)
    ga_edge_kernel<<<(NA * 64 + 255) / 256, 256, 0, stream>>>(
        x_a, f_v, ea_a2v, a2v_t,
        off_a, deg_a, csr_a, ga_W1, ga_b1, Aga, NA);

    // cut-node MLP -> output
    fa_node_kernel<<<(NA + 255) / 256, 256, 0, stream>>>(
        x_a, Aga, deg_a,
        fa_W1, fa_b1, fa_W2, fa_b2, Mga, bgav, (float*)d_out, NA);
}

// Round 5
// 1014.020 us; speedup vs baseline: 1.3717x; 1.3717x over previous
//
#include <hip/hip_runtime.h>

#define HD 32   // hidden/emb dim
#define ND 16   // node feature dim
#define ED 8    // edge feature dim

// ===========================================================================
// CSR build: histogram -> parallel 3-pass exclusive scan (fused) -> scatter
// ===========================================================================
__global__ __launch_bounds__(256) void hist_kernel(
    const int* __restrict__ keys, int* __restrict__ deg, int n)
{
    int i = blockIdx.x * 256 + threadIdx.x;
    if (i < n) atomicAdd(&deg[keys[i]], 1);
}

__global__ __launch_bounds__(256) void hist2_kernel(
    const int* __restrict__ k1, int* __restrict__ d1,
    const int* __restrict__ k2, int* __restrict__ d2, int n)
{
    int i = blockIdx.x * 256 + threadIdx.x;
    if (i < n) { atomicAdd(&d1[k1[i]], 1); atomicAdd(&d2[k2[i]], 1); }
}

// pass 1 (fused over 3 arrays): per-1024-chunk sums
__global__ __launch_bounds__(256) void scan_p1f(
    const int* __restrict__ dg, const int* __restrict__ dh, const int* __restrict__ da,
    int* __restrict__ cg, int* __restrict__ chs, int* __restrict__ ca,
    int nV, int nA, int chunksV)
{
    int b = blockIdx.x;
    const int* in; int* cs; int n; int c;
    if (b < chunksV)            { in = dg; cs = cg;  n = nV; c = b; }
    else if (b < 2 * chunksV)   { in = dh; cs = chs; n = nV; c = b - chunksV; }
    else                        { in = da; cs = ca;  n = nA; c = b - 2 * chunksV; }

    int i0 = c * 1024 + threadIdx.x * 4;
    int s = 0;
#pragma unroll
    for (int j = 0; j < 4; j++) { int i = i0 + j; if (i < n) s += in[i]; }
#pragma unroll
    for (int m = 1; m < 64; m <<= 1) s += __shfl_xor(s, m, 64);
    __shared__ int ws[4];
    if ((threadIdx.x & 63) == 0) ws[threadIdx.x >> 6] = s;
    __syncthreads();
    if (threadIdx.x == 0) cs[c] = ws[0] + ws[1] + ws[2] + ws[3];
}

// pass 2: exclusive scan of chunk sums in place (n <= 1024), 3 arrays
__device__ __forceinline__ void exscan_block(int* __restrict__ c, int n)
{
    int i = threadIdx.x;
    int v = (i < n) ? c[i] : 0;
    int x = v;
    int lane = i & 63, wid = i >> 6;
#pragma unroll
    for (int dd = 1; dd < 64; dd <<= 1) {
        int y = __shfl_up(x, dd, 64);
        if (lane >= dd) x += y;
    }
    __shared__ int ws[16];
    if (lane == 63) ws[wid] = x;
    __syncthreads();
    if (i == 0) {
        int a = 0;
#pragma unroll
        for (int w = 0; w < 16; w++) { int t = ws[w]; ws[w] = a; a += t; }
    }
    __syncthreads();
    int excl = ws[wid] + x - v;
    if (i < n) c[i] = excl;
}

__global__ __launch_bounds__(1024) void scan_p2(
    int* c0, int n0, int* c1, int n1, int* c2, int n2)
{
    if (blockIdx.x == 0)      exscan_block(c0, n0);
    else if (blockIdx.x == 1) exscan_block(c1, n1);
    else                      exscan_block(c2, n2);
}

// pass 3 (fused): per-chunk exclusive prefix + chunk base -> off, cur
__global__ __launch_bounds__(1024) void scan_p3f(
    const int* __restrict__ dg, const int* __restrict__ dh, const int* __restrict__ da,
    const int* __restrict__ cg, const int* __restrict__ chs, const int* __restrict__ ca,
    int* __restrict__ og, int* __restrict__ oh, int* __restrict__ oa,
    int* __restrict__ ug, int* __restrict__ uh, int* __restrict__ ua,
    int nV, int nA, int chunksV)
{
    int b = blockIdx.x;
    const int* deg; const int* cbase; int* off; int* cur; int n; int c;
    if (b < chunksV)          { deg = dg; cbase = cg;  off = og; cur = ug; n = nV; c = b; }
    else if (b < 2 * chunksV) { deg = dh; cbase = chs; off = oh; cur = uh; n = nV; c = b - chunksV; }
    else                      { deg = da; cbase = ca;  off = oa; cur = ua; n = nA; c = b - 2 * chunksV; }

    int i = c * 1024 + threadIdx.x;
    int v = (i < n) ? deg[i] : 0;
    int x = v;
    int lane = threadIdx.x & 63, wid = threadIdx.x >> 6;
#pragma unroll
    for (int dd = 1; dd < 64; dd <<= 1) {
        int y = __shfl_up(x, dd, 64);
        if (lane >= dd) x += y;
    }
    __shared__ int ws[16];
    if (lane == 63) ws[wid] = x;
    __syncthreads();
    if (threadIdx.x == 0) {
        int a = 0;
#pragma unroll
        for (int w = 0; w < 16; w++) { int t = ws[w]; ws[w] = a; a += t; }
    }
    __syncthreads();
    int excl = cbase[c] + ws[wid] + x - v;
    if (i < n) { off[i] = excl; cur[i] = excl; }
}

__global__ __launch_bounds__(256) void scatter_kernel(
    const int* __restrict__ keys, int* __restrict__ cur,
    int* __restrict__ csr, int n)
{
    int i = blockIdx.x * 256 + threadIdx.x;
    if (i < n) { int p = atomicAdd(&cur[keys[i]], 1); csr[p] = i; }
}

__global__ __launch_bounds__(256) void scatter2_kernel(
    const int* __restrict__ k1, int* __restrict__ cur1, int* __restrict__ csr1,
    const int* __restrict__ k2, int* __restrict__ cur2, int* __restrict__ csr2, int n)
{
    int i = blockIdx.x * 256 + threadIdx.x;
    if (i < n) {
        int p = atomicAdd(&cur1[k1[i]], 1); csr1[p] = i;
        int q = atomicAdd(&cur2[k2[i]], 1); csr2[q] = i;
    }
}

// ===========================================================================
// Fused precompute: per-node layer-1 partials + folded layer-2 matrices.
//  PXg[v]=gvb1+xv.gvW1[0:16]   PXh[v]=hvb1+xv.hvW1[0:16]
//  PCg[c]=xc.gvW1[16:32]       PAh[a]=xa.hvW1[16:32]
//  PXga[a]=gab1+xa.gaW1[0:16]
//  Mg=gvW2@fvW1[16:48] bg=gvb2@fvW1[16:48]; Mh,bh; Mga=gaW2@faW1[16:48], bga
// ===========================================================================
__global__ __launch_bounds__(256) void precompA_kernel(
    const float* __restrict__ xv, const float* __restrict__ xc, const float* __restrict__ xa,
    const float* __restrict__ gvW1, const float* __restrict__ gvb1,
    const float* __restrict__ hvW1, const float* __restrict__ hvb1,
    const float* __restrict__ gaW1, const float* __restrict__ gab1,
    const float* __restrict__ gvW2, const float* __restrict__ gvb2,
    const float* __restrict__ hvW2, const float* __restrict__ hvb2,
    const float* __restrict__ gaW2, const float* __restrict__ gab2,
    const float* __restrict__ fvW1, const float* __restrict__ faW1,
    float* __restrict__ PXg, float* __restrict__ PXh,
    float* __restrict__ PCg, float* __restrict__ PAh, float* __restrict__ PXga,
    float* __restrict__ Mg, float* __restrict__ bg,
    float* __restrict__ Mh, float* __restrict__ bh,
    float* __restrict__ Mga, float* __restrict__ bga,
    int nV, int nC, int nA)
{
    int bV = (nV + 255) / 256, bC = (nC + 255) / 256, bA = (nA + 255) / 256;
    int b = blockIdx.x;

    if (b < bV) {
        int v = b * 256 + threadIdx.x;
        if (v >= nV) return;
        float x[ND];
        const float4* p = reinterpret_cast<const float4*>(xv + (size_t)v * ND);
#pragma unroll
        for (int q = 0; q < 4; q++) {
            float4 t = p[q];
            x[4*q+0] = t.x; x[4*q+1] = t.y; x[4*q+2] = t.z; x[4*q+3] = t.w;
        }
        float g[HD], h[HD];
#pragma unroll
        for (int ch = 0; ch < HD; ch++) {
            float tg = gvb1[ch], th = hvb1[ch];
#pragma unroll
            for (int i = 0; i < ND; i++) {
                tg = fmaf(x[i], gvW1[i * HD + ch], tg);
                th = fmaf(x[i], hvW1[i * HD + ch], th);
            }
            g[ch] = tg; h[ch] = th;
        }
        float4* dg4 = reinterpret_cast<float4*>(PXg + (size_t)v * HD);
        float4* dh4 = reinterpret_cast<float4*>(PXh + (size_t)v * HD);
#pragma unroll
        for (int q = 0; q < 8; q++) {
            dg4[q] = make_float4(g[4*q+0], g[4*q+1], g[4*q+2], g[4*q+3]);
            dh4[q] = make_float4(h[4*q+0], h[4*q+1], h[4*q+2], h[4*q+3]);
        }
    } else if (b < bV + bC) {
        int c = (b - bV) * 256 + threadIdx.x;
        if (c >= nC) return;
        float x[ND];
        const float4* p = reinterpret_cast<const float4*>(xc + (size_t)c * ND);
#pragma unroll
        for (int q = 0; q < 4; q++) {
            float4 t = p[q];
            x[4*q+0] = t.x; x[4*q+1] = t.y; x[4*q+2] = t.z; x[4*q+3] = t.w;
        }
        float g[HD];
#pragma unroll
        for (int ch = 0; ch < HD; ch++) {
            float tg = 0.f;
#pragma unroll
            for (int i = 0; i < ND; i++) tg = fmaf(x[i], gvW1[(ND + i) * HD + ch], tg);
            g[ch] = tg;
        }
        float4* d4 = reinterpret_cast<float4*>(PCg + (size_t)c * HD);
#pragma unroll
        for (int q = 0; q < 8; q++)
            d4[q] = make_float4(g[4*q+0], g[4*q+1], g[4*q+2], g[4*q+3]);
    } else if (b < bV + bC + bA) {
        int a = (b - bV - bC) * 256 + threadIdx.x;
        if (a >= nA) return;
        float x[ND];
        const float4* p = reinterpret_cast<const float4*>(xa + (size_t)a * ND);
#pragma unroll
        for (int q = 0; q < 4; q++) {
            float4 t = p[q];
            x[4*q+0] = t.x; x[4*q+1] = t.y; x[4*q+2] = t.z; x[4*q+3] = t.w;
        }
        float h[HD], g[HD];
#pragma unroll
        for (int ch = 0; ch < HD; ch++) {
            float th = 0.f, tg = gab1[ch];
#pragma unroll
            for (int i = 0; i < ND; i++) {
                th = fmaf(x[i], hvW1[(ND + i) * HD + ch], th);
                tg = fmaf(x[i], gaW1[i * HD + ch], tg);
            }
            h[ch] = th; g[ch] = tg;
        }
        float4* dh4 = reinterpret_cast<float4*>(PAh + (size_t)a * HD);
        float4* dg4 = reinterpret_cast<float4*>(PXga + (size_t)a * HD);
#pragma unroll
        for (int q = 0; q < 8; q++) {
            dh4[q] = make_float4(h[4*q+0], h[4*q+1], h[4*q+2], h[4*q+3]);
            dg4[q] = make_float4(g[4*q+0], g[4*q+1], g[4*q+2], g[4*q+3]);
        }
    } else {
        // folded layer-2 matrices
        int t = threadIdx.x;
        for (int idx = t; idx < HD * HD; idx += 256) {
            int c = idx >> 5, h = idx & 31;
            float sg = 0.f, sh = 0.f, sa = 0.f;
#pragma unroll
            for (int o = 0; o < HD; o++) {
                sg = fmaf(gvW2[c * HD + o], fvW1[(ND + o) * HD + h], sg);
                sh = fmaf(hvW2[c * HD + o], fvW1[(ND + HD + o) * HD + h], sh);
                sa = fmaf(gaW2[c * HD + o], faW1[(ND + o) * HD + h], sa);
            }
            Mg[idx] = sg; Mh[idx] = sh; Mga[idx] = sa;
        }
        if (t < HD) {
            float sg = 0.f, sh = 0.f, sa = 0.f;
#pragma unroll
            for (int o = 0; o < HD; o++) {
                sg = fmaf(gvb2[o], fvW1[(ND + o) * HD + t], sg);
                sh = fmaf(hvb2[o], fvW1[(ND + HD + o) * HD + t], sh);
                sa = fmaf(gab2[o], faW1[(ND + o) * HD + t], sa);
            }
            bg[t] = sg; bh[t] = sh; bga[t] = sa;
        }
    }
}

// ===========================================================================
// fv edge kernel: 8 lanes per variable node, lane = edge-slot.
// Per edge: acc[ch] += relu(PXg[ch] + PCg[s][ch] + ea . W[32:40][ch]).
// 64 independent gather chains per wave; px/acc register-resident.
// ===========================================================================
__global__ __launch_bounds__(256, 4) void fv_edge_kernel(
    const float* __restrict__ PXg, const float* __restrict__ PCg,
    const float* __restrict__ PXh, const float* __restrict__ PAh,
    const int* __restrict__ c2v_src, const int* __restrict__ a2v_src,
    const float* __restrict__ ea_c, const float* __restrict__ ea_a,
    const int* __restrict__ off_g, const int* __restrict__ deg_g, const int* __restrict__ csr_g,
    const int* __restrict__ off_h, const int* __restrict__ deg_h, const int* __restrict__ csr_h,
    const float* __restrict__ gvW1, const float* __restrict__ hvW1,
    float* __restrict__ Ag, float* __restrict__ Ah, int nV)
{
    int gid = blockIdx.x * 256 + threadIdx.x;
    int v   = gid >> 3;
    int sub = threadIdx.x & 7;
    if (v >= nV) return;

    float px[HD], acc[HD];

    // ---------------- g: c2v edges ----------------
    {
        const float4* pp = reinterpret_cast<const float4*>(PXg + (size_t)v * HD);
#pragma unroll
        for (int q = 0; q < 8; q++) {
            float4 t = pp[q];
            px[4*q+0] = t.x; px[4*q+1] = t.y; px[4*q+2] = t.z; px[4*q+3] = t.w;
        }
#pragma unroll
        for (int ch = 0; ch < HD; ch++) acc[ch] = 0.f;

        int base = off_g[v], d = deg_g[v];
        for (int k = sub; k < d; k += 8) {
            int e = csr_g[base + k];
            int s = c2v_src[e];
            float pc[HD], ev[ED];
            {
                const float4* p = reinterpret_cast<const float4*>(PCg + (size_t)s * HD);
#pragma unroll
                for (int q = 0; q < 8; q++) {
                    float4 t = p[q];
                    pc[4*q+0] = t.x; pc[4*q+1] = t.y; pc[4*q+2] = t.z; pc[4*q+3] = t.w;
                }
                const float4* pe = reinterpret_cast<const float4*>(ea_c + (size_t)e * ED);
                float4 q0 = pe[0], q1 = pe[1];
                ev[0]=q0.x; ev[1]=q0.y; ev[2]=q0.z; ev[3]=q0.w;
                ev[4]=q1.x; ev[5]=q1.y; ev[6]=q1.z; ev[7]=q1.w;
            }
#pragma unroll
            for (int ch = 0; ch < HD; ch++) {
                float t = px[ch] + pc[ch];
#pragma unroll
                for (int i = 0; i < ED; i++) t = fmaf(ev[i], gvW1[(2 * ND + i) * HD + ch], t);
                acc[ch] += fmaxf(t, 0.f);
            }
        }
#pragma unroll
        for (int m = 1; m < 8; m <<= 1) {
#pragma unroll
            for (int ch = 0; ch < HD; ch++) acc[ch] += __shfl_xor(acc[ch], m, 64);
        }
        if (sub == 0) {
            float4* dst = reinterpret_cast<float4*>(Ag + (size_t)v * HD);
#pragma unroll
            for (int q = 0; q < 8; q++)
                dst[q] = make_float4(acc[4*q+0], acc[4*q+1], acc[4*q+2], acc[4*q+3]);
        }
    }

    // ---------------- h: a2v edges ----------------
    {
        const float4* pp = reinterpret_cast<const float4*>(PXh + (size_t)v * HD);
#pragma unroll
        for (int q = 0; q < 8; q++) {
            float4 t = pp[q];
            px[4*q+0] = t.x; px[4*q+1] = t.y; px[4*q+2] = t.z; px[4*q+3] = t.w;
        }
#pragma unroll
        for (int ch = 0; ch < HD; ch++) acc[ch] = 0.f;

        int base = off_h[v], d = deg_h[v];
        for (int k = sub; k < d; k += 8) {
            int e = csr_h[base + k];
            int s = a2v_src[e];
            float pc[HD], ev[ED];
            {
                const float4* p = reinterpret_cast<const float4*>(PAh + (size_t)s * HD);
#pragma unroll
                for (int q = 0; q < 8; q++) {
                    float4 t = p[q];
                    pc[4*q+0] = t.x; pc[4*q+1] = t.y; pc[4*q+2] = t.z; pc[4*q+3] = t.w;
                }
                const float4* pe = reinterpret_cast<const float4*>(ea_a + (size_t)e * ED);
                float4 q0 = pe[0], q1 = pe[1];
                ev[0]=q0.x; ev[1]=q0.y; ev[2]=q0.z; ev[3]=q0.w;
                ev[4]=q1.x; ev[5]=q1.y; ev[6]=q1.z; ev[7]=q1.w;
            }
#pragma unroll
            for (int ch = 0; ch < HD; ch++) {
                float t = px[ch] + pc[ch];
#pragma unroll
                for (int i = 0; i < ED; i++) t = fmaf(ev[i], hvW1[(2 * ND + i) * HD + ch], t);
                acc[ch] += fmaxf(t, 0.f);
            }
        }
#pragma unroll
        for (int m = 1; m < 8; m <<= 1) {
#pragma unroll
            for (int ch = 0; ch < HD; ch++) acc[ch] += __shfl_xor(acc[ch], m, 64);
        }
        if (sub == 0) {
            float4* dst = reinterpret_cast<float4*>(Ah + (size_t)v * HD);
#pragma unroll
            for (int q = 0; q < 8; q++)
                dst[q] = make_float4(acc[4*q+0], acc[4*q+1], acc[4*q+2], acc[4*q+3]);
        }
    }
}

// ===========================================================================
// fv node kernel: one thread per v; computes f_v in registers and directly
// emits PFga[v] = f_v . gaW1[16:48]  (f_v never materialized).
// ===========================================================================
__global__ __launch_bounds__(256, 3) void fv_node_kernel(
    const float* __restrict__ xv,
    const float* __restrict__ Ag, const float* __restrict__ Ah,
    const int* __restrict__ deg_g, const int* __restrict__ deg_h,
    const float* __restrict__ fvW1, const float* __restrict__ fvb1,
    const float* __restrict__ fvW2, const float* __restrict__ fvb2,
    const float* __restrict__ Mg, const float* __restrict__ bg,
    const float* __restrict__ Mh, const float* __restrict__ bh,
    const float* __restrict__ gaW1,
    float* __restrict__ PFga, int nV)
{
    int v = blockIdx.x * 256 + threadIdx.x;
    if (v >= nV) return;

    float xvr[ND], agr[HD], ahr[HD];
    {
        const float4* p = reinterpret_cast<const float4*>(xv + (size_t)v * ND);
#pragma unroll
        for (int q = 0; q < 4; q++) {
            float4 t = p[q];
            xvr[4*q+0] = t.x; xvr[4*q+1] = t.y; xvr[4*q+2] = t.z; xvr[4*q+3] = t.w;
        }
        const float4* pg = reinterpret_cast<const float4*>(Ag + (size_t)v * HD);
        const float4* ph = reinterpret_cast<const float4*>(Ah + (size_t)v * HD);
#pragma unroll
        for (int q = 0; q < 8; q++) {
            float4 t = pg[q];
            agr[4*q+0] = t.x; agr[4*q+1] = t.y; agr[4*q+2] = t.z; agr[4*q+3] = t.w;
            float4 u = ph[q];
            ahr[4*q+0] = u.x; ahr[4*q+1] = u.y; ahr[4*q+2] = u.z; ahr[4*q+3] = u.w;
        }
    }
    int dg = deg_g[v], dh = deg_h[v];
    float invg = dg > 0 ? 1.f / (float)dg : 0.f;
    float invh = dh > 0 ? 1.f / (float)dh : 0.f;
    float bgk  = dg > 0 ? 1.f : 0.f;
    float bhk  = dh > 0 ? 1.f : 0.f;

    float hid[HD];
#pragma unroll
    for (int h = 0; h < HD; h++) {
        float t = fvb1[h] + bgk * bg[h] + bhk * bh[h];
#pragma unroll
        for (int i = 0; i < ND; i++) t = fmaf(xvr[i], fvW1[i * HD + h], t);
        float sg = 0.f, sh = 0.f;
#pragma unroll
        for (int c = 0; c < HD; c++) {
            sg = fmaf(agr[c], Mg[c * HD + h], sg);
            sh = fmaf(ahr[c], Mh[c * HD + h], sh);
        }
        t += invg * sg + invh * sh;
        hid[h] = fmaxf(t, 0.f);
    }
    float fv[HD];
#pragma unroll
    for (int o = 0; o < HD; o++) {
        float t = fvb2[o];
#pragma unroll
        for (int h = 0; h < HD; h++) t = fmaf(hid[h], fvW2[h * HD + o], t);
        fv[o] = t;
    }
    // PFga = f_v . gaW1[16:48]
    float pf[HD];
#pragma unroll
    for (int ch = 0; ch < HD; ch++) {
        float t = 0.f;
#pragma unroll
        for (int i = 0; i < HD; i++) t = fmaf(fv[i], gaW1[(ND + i) * HD + ch], t);
        pf[ch] = t;
    }
    float4* dst = reinterpret_cast<float4*>(PFga + (size_t)v * HD);
#pragma unroll
    for (int q = 0; q < 8; q++)
        dst[q] = make_float4(pf[4*q+0], pf[4*q+1], pf[4*q+2], pf[4*q+3]);
}

// ===========================================================================
// ga edge kernel: one full wave (64 lanes) per cut node, lane = edge-slot.
// Per edge: acc[ch] += relu(PXga[ch] + PFga[t][ch] + ea . gaW1[48:56][ch]).
// ===========================================================================
__global__ __launch_bounds__(256, 4) void ga_edge_kernel(
    const float* __restrict__ PXga, const float* __restrict__ PFga,
    const float* __restrict__ ea_a,
    const int* __restrict__ a2v_tgt,
    const int* __restrict__ off_a, const int* __restrict__ deg_a, const int* __restrict__ csr_a,
    const float* __restrict__ gaW1,
    float* __restrict__ Aga, int nA)
{
    int gid = blockIdx.x * 256 + threadIdx.x;
    int a   = gid >> 6;
    int ln  = threadIdx.x & 63;
    if (a >= nA) return;

    float px[HD], acc[HD];
    {
        const float4* pp = reinterpret_cast<const float4*>(PXga + (size_t)a * HD);
#pragma unroll
        for (int q = 0; q < 8; q++) {
            float4 t = pp[q];
            px[4*q+0] = t.x; px[4*q+1] = t.y; px[4*q+2] = t.z; px[4*q+3] = t.w;
        }
    }
#pragma unroll
    for (int ch = 0; ch < HD; ch++) acc[ch] = 0.f;

    int base = off_a[a], d = deg_a[a];
    for (int k = ln; k < d; k += 64) {
        int e = csr_a[base + k];
        int t = a2v_tgt[e];
        float pf[HD], ev[ED];
        {
            const float4* p = reinterpret_cast<const float4*>(PFga + (size_t)t * HD);
#pragma unroll
            for (int q = 0; q < 8; q++) {
                float4 w = p[q];
                pf[4*q+0] = w.x; pf[4*q+1] = w.y; pf[4*q+2] = w.z; pf[4*q+3] = w.w;
            }
            const float4* pe = reinterpret_cast<const float4*>(ea_a + (size_t)e * ED);
            float4 q0 = pe[0], q1 = pe[1];
            ev[0]=q0.x; ev[1]=q0.y; ev[2]=q0.z; ev[3]=q0.w;
            ev[4]=q1.x; ev[5]=q1.y; ev[6]=q1.z; ev[7]=q1.w;
        }
#pragma unroll
        for (int ch = 0; ch < HD; ch++) {
            float t2 = px[ch] + pf[ch];
#pragma unroll
            for (int i = 0; i < ED; i++) t2 = fmaf(ev[i], gaW1[(ND + HD + i) * HD + ch], t2);
            acc[ch] += fmaxf(t2, 0.f);
        }
    }
#pragma unroll
    for (int m = 1; m < 64; m <<= 1) {
#pragma unroll
        for (int ch = 0; ch < HD; ch++) acc[ch] += __shfl_xor(acc[ch], m, 64);
    }
    if (ln == 0) {
        float4* dst = reinterpret_cast<float4*>(Aga + (size_t)a * HD);
#pragma unroll
        for (int q = 0; q < 8; q++)
            dst[q] = make_float4(acc[4*q+0], acc[4*q+1], acc[4*q+2], acc[4*q+3]);
    }
}

// ===========================================================================
// fa node kernel: one thread per a node -> final output.
// ===========================================================================
__global__ __launch_bounds__(256) void fa_node_kernel(
    const float* __restrict__ xa,
    const float* __restrict__ Aga, const int* __restrict__ deg_a,
    const float* __restrict__ faW1, const float* __restrict__ fab1,
    const float* __restrict__ faW2, const float* __restrict__ fab2,
    const float* __restrict__ Mga, const float* __restrict__ bga,
    float* __restrict__ out, int nA)
{
    int a = blockIdx.x * 256 + threadIdx.x;
    if (a >= nA) return;

    float xar[ND], agr[HD];
    {
        const float4* p = reinterpret_cast<const float4*>(xa + (size_t)a * ND);
#pragma unroll
        for (int q = 0; q < 4; q++) {
            float4 t = p[q];
            xar[4*q+0] = t.x; xar[4*q+1] = t.y; xar[4*q+2] = t.z; xar[4*q+3] = t.w;
        }
        const float4* pg = reinterpret_cast<const float4*>(Aga + (size_t)a * HD);
#pragma unroll
        for (int q = 0; q < 8; q++) {
            float4 t = pg[q];
            agr[4*q+0] = t.x; agr[4*q+1] = t.y; agr[4*q+2] = t.z; agr[4*q+3] = t.w;
        }
    }
    int d = deg_a[a];
    float inv = d > 0 ? 1.f / (float)d : 0.f;
    float bk  = d > 0 ? 1.f : 0.f;

    float hid[HD];
#pragma unroll
    for (int h = 0; h < HD; h++) {
        float t = fab1[h] + bk * bga[h];
#pragma unroll
        for (int i = 0; i < ND; i++) t = fmaf(xar[i], faW1[i * HD + h], t);
        float s = 0.f;
#pragma unroll
        for (int c = 0; c < HD; c++) s = fmaf(agr[c], Mga[c * HD + h], s);
        t += inv * s;
        hid[h] = fmaxf(t, 0.f);
    }
    float* ob = out + (size_t)a * HD;
#pragma unroll
    for (int o = 0; o < HD; o++) {
        float t = fab2[o];
#pragma unroll
        for (int h = 0; h < HD; h++) t = fmaf(hid[h], faW2[h * HD + o], t);
        ob[o] = t;
    }
}

// ===========================================================================
extern "C" void kernel_launch(void* const* d_in, const int* in_sizes, int n_in,
                              void* d_out, int out_size, void* d_ws, size_t ws_size,
                              hipStream_t stream) {
    const float* x_c    = (const float*)d_in[0];
    const float* x_v    = (const float*)d_in[1];
    const float* x_a    = (const float*)d_in[2];
    const int*   ei_c2v = (const int*)d_in[3];
    const int*   ei_a2v = (const int*)d_in[4];
    const float* ea_c2v = (const float*)d_in[5];
    const float* ea_a2v = (const float*)d_in[6];
    const float *gv_W1=(const float*)d_in[7],  *gv_b1=(const float*)d_in[8],
                *gv_W2=(const float*)d_in[9],  *gv_b2=(const float*)d_in[10];
    const float *hv_W1=(const float*)d_in[11], *hv_b1=(const float*)d_in[12],
                *hv_W2=(const float*)d_in[13], *hv_b2=(const float*)d_in[14];
    const float *fv_W1=(const float*)d_in[15], *fv_b1=(const float*)d_in[16],
                *fv_W2=(const float*)d_in[17], *fv_b2=(const float*)d_in[18];
    const float *ga_W1=(const float*)d_in[19], *ga_b1=(const float*)d_in[20],
                *ga_W2=(const float*)d_in[21], *ga_b2=(const float*)d_in[22];
    const float *fa_W1=(const float*)d_in[23], *fa_b1=(const float*)d_in[24],
                *fa_W2=(const float*)d_in[25], *fa_b2=(const float*)d_in[26];

    const int NC = in_sizes[0] / ND;
    const int NV = in_sizes[1] / ND;
    const int NA = in_sizes[2] / ND;
    const int EC = in_sizes[3] / 2;
    const int EA = in_sizes[4] / 2;
    (void)n_in; (void)ws_size; (void)out_size;

    const int* c2v_s = ei_c2v;            // constraint side of c2v
    const int* c2v_t = ei_c2v + EC;       // variable side
    const int* a2v_s = ei_a2v;            // cut node side
    const int* a2v_t = ei_a2v + EA;       // variable side

    const int chunksV = (NV + 1023) / 1024;
    const int chunksA = (NA + 1023) / 1024;

    // Workspace layout (4B words)
    int* wsI = (int*)d_ws;
    int* deg_g = wsI;                 // NV
    int* deg_h = deg_g + NV;          // NV
    int* deg_a = deg_h + NV;          // NA
    int* off_g = deg_a + NA;          // NV
    int* off_h = off_g + NV;          // NV
    int* off_a = off_h + NV;          // NA
    int* cur_g = off_a + NA;          // NV
    int* cur_h = cur_g + NV;          // NV
    int* cur_a = cur_h + NV;          // NA
    int* csum_g = cur_a + NA;         // 1024
    int* csum_h = csum_g + 1024;      // 1024
    int* csum_a = csum_h + 1024;      // 1024
    int* csr_g = csum_a + 1024;       // EC
    int* csr_h = csr_g + EC;          // EA
    int* csr_a = csr_h + EA;          // EA
    float* PXg = (float*)(csr_a + EA);    // NV*HD  (aliased as PFga later)
    float* PXh = PXg + (size_t)NV * HD;   // NV*HD
    float* PCg = PXh + (size_t)NV * HD;   // NC*HD
    float* PAh = PCg + (size_t)NC * HD;   // NA*HD
    float* PXga= PAh + (size_t)NA * HD;   // NA*HD
    float* Ag  = PXga + (size_t)NA * HD;  // NV*HD
    float* Ah  = Ag + (size_t)NV * HD;    // NV*HD
    float* Aga = Ah + (size_t)NV * HD;    // NA*HD
    float* Mg  = Aga + (size_t)NA * HD;   // 1024
    float* Mh  = Mg + HD * HD;            // 1024
    float* Mga = Mh + HD * HD;            // 1024
    float* bgv = Mga + HD * HD;           // 32
    float* bhv = bgv + HD;                // 32
    float* bgav= bhv + HD;                // 32
    float* PFga = PXg;                    // alias: PXg dead after fv_edge

    // zero degree histograms only
    hipMemsetAsync(deg_g, 0, (size_t)(2 * NV + NA) * sizeof(int), stream);

    // fused precompute (node partials + folded matrices)
    {
        int bV = (NV + 255) / 256, bC = (NC + 255) / 256, bA = (NA + 255) / 256;
        precompA_kernel<<<bV + bC + bA + 1, 256, 0, stream>>>(
            x_v, x_c, x_a,
            gv_W1, gv_b1, hv_W1, hv_b1, ga_W1, ga_b1,
            gv_W2, gv_b2, hv_W2, hv_b2, ga_W2, ga_b2,
            fv_W1, fa_W1,
            PXg, PXh, PCg, PAh, PXga,
            Mg, bgv, Mh, bhv, Mga, bgav, NV, NC, NA);
    }

    // histograms
    hist_kernel<<<(EC + 255) / 256, 256, 0, stream>>>(c2v_t, deg_g, EC);
    hist2_kernel<<<(EA + 255) / 256, 256, 0, stream>>>(a2v_t, deg_h, a2v_s, deg_a, EA);

    // parallel exclusive scans (fused)
    scan_p1f<<<2 * chunksV + chunksA, 256, 0, stream>>>(
        deg_g, deg_h, deg_a, csum_g, csum_h, csum_a, NV, NA, chunksV);
    scan_p2<<<3, 1024, 0, stream>>>(csum_g, chunksV, csum_h, chunksV, csum_a, chunksA);
    scan_p3f<<<2 * chunksV + chunksA, 1024, 0, stream>>>(
        deg_g, deg_h, deg_a, csum_g, csum_h, csum_a,
        off_g, off_h, off_a, cur_g, cur_h, cur_a, NV, NA, chunksV);

    // scatter edge ids into CSR
    scatter_kernel<<<(EC + 255) / 256, 256, 0, stream>>>(c2v_t, cur_g, csr_g, EC);
    scatter2_kernel<<<(EA + 255) / 256, 256, 0, stream>>>(a2v_t, cur_h, csr_h,
                                                          a2v_s, cur_a, csr_a, EA);

    // variable-node edge aggregation (8 lanes/node, precomputed partials)
    fv_edge_kernel<<<(NV * 8 + 255) / 256, 256, 0, stream>>>(
        PXg, PCg, PXh, PAh, c2v_s, a2v_s, ea_c2v, ea_a2v,
        off_g, deg_g, csr_g, off_h, deg_h, csr_h,
        gv_W1, hv_W1, Ag, Ah, NV);

    // variable-node MLP -> PFga (f_v folded straight into ga layer-1 partial)
    fv_node_kernel<<<(NV + 255) / 256, 256, 0, stream>>>(
        x_v, Ag, Ah, deg_g, deg_h,
        fv_W1, fv_b1, fv_W2, fv_b2, Mg, bgv, Mh, bhv, ga_W1, PFga, NV);

    // cut-node edge aggregation (64 lanes/node)
    ga_edge_kernel<<<(NA * 64 + 255) / 256, 256, 0, stream>>>(
        PXga, PFga, ea_a2v, a2v_t,
        off_a, deg_a, csr_a, ga_W1, Aga, NA);

    // cut-node MLP -> output
    fa_node_kernel<<<(NA + 255) / 256, 256, 0, stream>>>(
        x_a, Aga, deg_a,
        fa_W1, fa_b1, fa_W2, fa_b2, Mga, bgav, (float*)d_out, NA);
}

// Round 6
// 686.386 us; speedup vs baseline: 2.0265x; 1.4773x over previous
//
#include <hip/hip_runtime.h>

#define HD 32   // hidden/emb dim
#define ND 16   // node feature dim
#define ED 8    // edge feature dim

// ===========================================================================
// CSR build: histogram -> parallel 3-pass exclusive scan (fused) -> scatter
// ===========================================================================
__global__ __launch_bounds__(256) void hist_kernel(
    const int* __restrict__ keys, int* __restrict__ deg, int n)
{
    int i = blockIdx.x * 256 + threadIdx.x;
    if (i < n) atomicAdd(&deg[keys[i]], 1);
}

__global__ __launch_bounds__(256) void hist2_kernel(
    const int* __restrict__ k1, int* __restrict__ d1,
    const int* __restrict__ k2, int* __restrict__ d2, int n)
{
    int i = blockIdx.x * 256 + threadIdx.x;
    if (i < n) { atomicAdd(&d1[k1[i]], 1); atomicAdd(&d2[k2[i]], 1); }
}

// pass 1 (fused over 3 arrays): per-1024-chunk sums
__global__ __launch_bounds__(256) void scan_p1f(
    const int* __restrict__ dg, const int* __restrict__ dh, const int* __restrict__ da,
    int* __restrict__ cg, int* __restrict__ chs, int* __restrict__ ca,
    int nV, int nA, int chunksV)
{
    int b = blockIdx.x;
    const int* in; int* cs; int n; int c;
    if (b < chunksV)            { in = dg; cs = cg;  n = nV; c = b; }
    else if (b < 2 * chunksV)   { in = dh; cs = chs; n = nV; c = b - chunksV; }
    else                        { in = da; cs = ca;  n = nA; c = b - 2 * chunksV; }

    int i0 = c * 1024 + threadIdx.x * 4;
    int s = 0;
#pragma unroll
    for (int j = 0; j < 4; j++) { int i = i0 + j; if (i < n) s += in[i]; }
#pragma unroll
    for (int m = 1; m < 64; m <<= 1) s += __shfl_xor(s, m, 64);
    __shared__ int ws[4];
    if ((threadIdx.x & 63) == 0) ws[threadIdx.x >> 6] = s;
    __syncthreads();
    if (threadIdx.x == 0) cs[c] = ws[0] + ws[1] + ws[2] + ws[3];
}

// pass 2: exclusive scan of chunk sums in place (n <= 1024), 3 arrays
__device__ __forceinline__ void exscan_block(int* __restrict__ c, int n)
{
    int i = threadIdx.x;
    int v = (i < n) ? c[i] : 0;
    int x = v;
    int lane = i & 63, wid = i >> 6;
#pragma unroll
    for (int dd = 1; dd < 64; dd <<= 1) {
        int y = __shfl_up(x, dd, 64);
        if (lane >= dd) x += y;
    }
    __shared__ int ws[16];
    if (lane == 63) ws[wid] = x;
    __syncthreads();
    if (i == 0) {
        int a = 0;
#pragma unroll
        for (int w = 0; w < 16; w++) { int t = ws[w]; ws[w] = a; a += t; }
    }
    __syncthreads();
    int excl = ws[wid] + x - v;
    if (i < n) c[i] = excl;
}

__global__ __launch_bounds__(1024) void scan_p2(
    int* c0, int n0, int* c1, int n1, int* c2, int n2)
{
    if (blockIdx.x == 0)      exscan_block(c0, n0);
    else if (blockIdx.x == 1) exscan_block(c1, n1);
    else                      exscan_block(c2, n2);
}

// pass 3 (fused): per-chunk exclusive prefix + chunk base -> off, cur
__global__ __launch_bounds__(1024) void scan_p3f(
    const int* __restrict__ dg, const int* __restrict__ dh, const int* __restrict__ da,
    const int* __restrict__ cg, const int* __restrict__ chs, const int* __restrict__ ca,
    int* __restrict__ og, int* __restrict__ oh, int* __restrict__ oa,
    int* __restrict__ ug, int* __restrict__ uh, int* __restrict__ ua,
    int nV, int nA, int chunksV)
{
    int b = blockIdx.x;
    const int* deg; const int* cbase; int* off; int* cur; int n; int c;
    if (b < chunksV)          { deg = dg; cbase = cg;  off = og; cur = ug; n = nV; c = b; }
    else if (b < 2 * chunksV) { deg = dh; cbase = chs; off = oh; cur = uh; n = nV; c = b - chunksV; }
    else                      { deg = da; cbase = ca;  off = oa; cur = ua; n = nA; c = b - 2 * chunksV; }

    int i = c * 1024 + threadIdx.x;
    int v = (i < n) ? deg[i] : 0;
    int x = v;
    int lane = threadIdx.x & 63, wid = threadIdx.x >> 6;
#pragma unroll
    for (int dd = 1; dd < 64; dd <<= 1) {
        int y = __shfl_up(x, dd, 64);
        if (lane >= dd) x += y;
    }
    __shared__ int ws[16];
    if (lane == 63) ws[wid] = x;
    __syncthreads();
    if (threadIdx.x == 0) {
        int a = 0;
#pragma unroll
        for (int w = 0; w < 16; w++) { int t = ws[w]; ws[w] = a; a += t; }
    }
    __syncthreads();
    int excl = cbase[c] + ws[wid] + x - v;
    if (i < n) { off[i] = excl; cur[i] = excl; }
}

__global__ __launch_bounds__(256) void scatter_kernel(
    const int* __restrict__ keys, int* __restrict__ cur,
    int* __restrict__ csr, int n)
{
    int i = blockIdx.x * 256 + threadIdx.x;
    if (i < n) { int p = atomicAdd(&cur[keys[i]], 1); csr[p] = i; }
}

__global__ __launch_bounds__(256) void scatter2_kernel(
    const int* __restrict__ k1, int* __restrict__ cur1, int* __restrict__ csr1,
    const int* __restrict__ k2, int* __restrict__ cur2, int* __restrict__ csr2, int n)
{
    int i = blockIdx.x * 256 + threadIdx.x;
    if (i < n) {
        int p = atomicAdd(&cur1[k1[i]], 1); csr1[p] = i;
        int q = atomicAdd(&cur2[k2[i]], 1); csr2[q] = i;
    }
}

// ===========================================================================
// Channel-parallel precompute. thread = (node, ch). Weights staged in LDS.
//  PXg[v][ch]=gvb1+xv.gvW1[0:16]    PXh[v][ch]=hvb1+xv.hvW1[0:16]
//  PCg[c][ch]=xc.gvW1[16:32]        PAh[a][ch]=xa.hvW1[16:32]
//  PXga[a][ch]=gab1+xa.gaW1[0:16]
// Plus folded matrices (last 4 blocks):
//  Mg=gvW2@fvW1[16:48], bg=gvb2@fvW1[16:48]; Mh,bh (rows 48:80)
//  Mga=gaW2@faW1[16:48], bga; Nfv=fvW2@gaW1[16:48], bfv=fvb2@gaW1[16:48]
// ===========================================================================
__global__ __launch_bounds__(256) void precompB_kernel(
    const float* __restrict__ xv, const float* __restrict__ xc, const float* __restrict__ xa,
    const float* __restrict__ gvW1, const float* __restrict__ gvb1,
    const float* __restrict__ hvW1, const float* __restrict__ hvb1,
    const float* __restrict__ gaW1, const float* __restrict__ gab1,
    const float* __restrict__ gvW2, const float* __restrict__ gvb2,
    const float* __restrict__ hvW2, const float* __restrict__ hvb2,
    const float* __restrict__ gaW2, const float* __restrict__ gab2,
    const float* __restrict__ fvW1, const float* __restrict__ fvW2,
    const float* __restrict__ fvb2, const float* __restrict__ faW1,
    float* __restrict__ PXg, float* __restrict__ PXh,
    float* __restrict__ PCg, float* __restrict__ PAh, float* __restrict__ PXga,
    float* __restrict__ Mg, float* __restrict__ bg,
    float* __restrict__ Mh, float* __restrict__ bh,
    float* __restrict__ Mga, float* __restrict__ bga,
    float* __restrict__ Nfv, float* __restrict__ bfv,
    int nV, int nC, int nA)
{
    int bV = (nV * 32 + 255) / 256, bC = (nC * 32 + 255) / 256, bA = (nA * 32 + 255) / 256;
    int b = blockIdx.x;
    int ch = threadIdx.x & 31;
    __shared__ float s0[512], s1[512];

    if (b < bV) {
        for (int i = threadIdx.x; i < 512; i += 256) { s0[i] = gvW1[i]; s1[i] = hvW1[i]; }
        __syncthreads();
        int v = (b * 256 + (int)threadIdx.x) >> 5;
        if (v >= nV) return;
        float x = (ch < ND) ? xv[(size_t)v * ND + ch] : 0.f;
        float pg = gvb1[ch], ph = hvb1[ch];
#pragma unroll
        for (int i = 0; i < ND; i++) {
            float xi = __shfl(x, i, 32);
            pg = fmaf(xi, s0[i * 32 + ch], pg);
            ph = fmaf(xi, s1[i * 32 + ch], ph);
        }
        PXg[(size_t)v * 32 + ch] = pg;
        PXh[(size_t)v * 32 + ch] = ph;
    } else if (b < bV + bC) {
        for (int i = threadIdx.x; i < 512; i += 256) s0[i] = gvW1[512 + i];
        __syncthreads();
        int c = ((b - bV) * 256 + (int)threadIdx.x) >> 5;
        if (c >= nC) return;
        float x = (ch < ND) ? xc[(size_t)c * ND + ch] : 0.f;
        float p = 0.f;
#pragma unroll
        for (int i = 0; i < ND; i++) p = fmaf(__shfl(x, i, 32), s0[i * 32 + ch], p);
        PCg[(size_t)c * 32 + ch] = p;
    } else if (b < bV + bC + bA) {
        for (int i = threadIdx.x; i < 512; i += 256) { s0[i] = hvW1[512 + i]; s1[i] = gaW1[i]; }
        __syncthreads();
        int a = ((b - bV - bC) * 256 + (int)threadIdx.x) >> 5;
        if (a >= nA) return;
        float x = (ch < ND) ? xa[(size_t)a * ND + ch] : 0.f;
        float ph = 0.f, pg = gab1[ch];
#pragma unroll
        for (int i = 0; i < ND; i++) {
            float xi = __shfl(x, i, 32);
            ph = fmaf(xi, s0[i * 32 + ch], ph);
            pg = fmaf(xi, s1[i * 32 + ch], pg);
        }
        PAh[(size_t)a * 32 + ch] = ph;
        PXga[(size_t)a * 32 + ch] = pg;
    } else {
        int m = b - (bV + bC + bA);
        const float *W2, *b2, *T; float *M, *bb; int toff;
        if (m == 0)      { W2 = gvW2; b2 = gvb2; T = fvW1; toff = ND;      M = Mg;  bb = bg;  }
        else if (m == 1) { W2 = hvW2; b2 = hvb2; T = fvW1; toff = ND + HD; M = Mh;  bb = bh;  }
        else if (m == 2) { W2 = gaW2; b2 = gab2; T = faW1; toff = ND;      M = Mga; bb = bga; }
        else             { W2 = fvW2; b2 = fvb2; T = gaW1; toff = ND;      M = Nfv; bb = bfv; }
        for (int idx = threadIdx.x; idx < 1024; idx += 256) {
            int c = idx >> 5, h = idx & 31;
            float s = 0.f;
#pragma unroll
            for (int o = 0; o < HD; o++) s = fmaf(W2[c * HD + o], T[(toff + o) * HD + h], s);
            M[idx] = s;
        }
        if (threadIdx.x < HD) {
            int h = threadIdx.x;
            float s = 0.f;
#pragma unroll
            for (int o = 0; o < HD; o++) s = fmaf(b2[o], T[(toff + o) * HD + h], s);
            bb[h] = s;
        }
    }
}

// ===========================================================================
// fv edge kernel: 8 lanes per variable node, lane = edge-slot.
// Per edge: acc[ch] += relu(PXg[ch] + PCg[s][ch] + ea . W[32:40][ch]).
// ===========================================================================
__global__ __launch_bounds__(256, 4) void fv_edge_kernel(
    const float* __restrict__ PXg, const float* __restrict__ PCg,
    const float* __restrict__ PXh, const float* __restrict__ PAh,
    const int* __restrict__ c2v_src, const int* __restrict__ a2v_src,
    const float* __restrict__ ea_c, const float* __restrict__ ea_a,
    const int* __restrict__ off_g, const int* __restrict__ deg_g, const int* __restrict__ csr_g,
    const int* __restrict__ off_h, const int* __restrict__ deg_h, const int* __restrict__ csr_h,
    const float* __restrict__ gvW1, const float* __restrict__ hvW1,
    float* __restrict__ Ag, float* __restrict__ Ah, int nV)
{
    int gid = blockIdx.x * 256 + threadIdx.x;
    int v   = gid >> 3;
    int sub = threadIdx.x & 7;
    if (v >= nV) return;

    float px[HD], acc[HD];

    // ---------------- g: c2v edges ----------------
    {
        const float4* pp = reinterpret_cast<const float4*>(PXg + (size_t)v * HD);
#pragma unroll
        for (int q = 0; q < 8; q++) {
            float4 t = pp[q];
            px[4*q+0] = t.x; px[4*q+1] = t.y; px[4*q+2] = t.z; px[4*q+3] = t.w;
        }
#pragma unroll
        for (int ch = 0; ch < HD; ch++) acc[ch] = 0.f;

        int base = off_g[v], d = deg_g[v];
        for (int k = sub; k < d; k += 8) {
            int e = csr_g[base + k];
            int s = c2v_src[e];
            float pc[HD], ev[ED];
            {
                const float4* p = reinterpret_cast<const float4*>(PCg + (size_t)s * HD);
#pragma unroll
                for (int q = 0; q < 8; q++) {
                    float4 t = p[q];
                    pc[4*q+0] = t.x; pc[4*q+1] = t.y; pc[4*q+2] = t.z; pc[4*q+3] = t.w;
                }
                const float4* pe = reinterpret_cast<const float4*>(ea_c + (size_t)e * ED);
                float4 q0 = pe[0], q1 = pe[1];
                ev[0]=q0.x; ev[1]=q0.y; ev[2]=q0.z; ev[3]=q0.w;
                ev[4]=q1.x; ev[5]=q1.y; ev[6]=q1.z; ev[7]=q1.w;
            }
#pragma unroll
            for (int ch = 0; ch < HD; ch++) {
                float t = px[ch] + pc[ch];
#pragma unroll
                for (int i = 0; i < ED; i++) t = fmaf(ev[i], gvW1[(2 * ND + i) * HD + ch], t);
                acc[ch] += fmaxf(t, 0.f);
            }
        }
#pragma unroll
        for (int m = 1; m < 8; m <<= 1) {
#pragma unroll
            for (int ch = 0; ch < HD; ch++) acc[ch] += __shfl_xor(acc[ch], m, 64);
        }
        if (sub == 0) {
            float4* dst = reinterpret_cast<float4*>(Ag + (size_t)v * HD);
#pragma unroll
            for (int q = 0; q < 8; q++)
                dst[q] = make_float4(acc[4*q+0], acc[4*q+1], acc[4*q+2], acc[4*q+3]);
        }
    }

    // ---------------- h: a2v edges ----------------
    {
        const float4* pp = reinterpret_cast<const float4*>(PXh + (size_t)v * HD);
#pragma unroll
        for (int q = 0; q < 8; q++) {
            float4 t = pp[q];
            px[4*q+0] = t.x; px[4*q+1] = t.y; px[4*q+2] = t.z; px[4*q+3] = t.w;
        }
#pragma unroll
        for (int ch = 0; ch < HD; ch++) acc[ch] = 0.f;

        int base = off_h[v], d = deg_h[v];
        for (int k = sub; k < d; k += 8) {
            int e = csr_h[base + k];
            int s = a2v_src[e];
            float pc[HD], ev[ED];
            {
                const float4* p = reinterpret_cast<const float4*>(PAh + (size_t)s * HD);
#pragma unroll
                for (int q = 0; q < 8; q++) {
                    float4 t = p[q];
                    pc[4*q+0] = t.x; pc[4*q+1] = t.y; pc[4*q+2] = t.z; pc[4*q+3] = t.w;
                }
                const float4* pe = reinterpret_cast<const float4*>(ea_a + (size_t)e * ED);
                float4 q0 = pe[0], q1 = pe[1];
                ev[0]=q0.x; ev[1]=q0.y; ev[2]=q0.z; ev[3]=q0.w;
                ev[4]=q1.x; ev[5]=q1.y; ev[6]=q1.z; ev[7]=q1.w;
            }
#pragma unroll
            for (int ch = 0; ch < HD; ch++) {
                float t = px[ch] + pc[ch];
#pragma unroll
                for (int i = 0; i < ED; i++) t = fmaf(ev[i], hvW1[(2 * ND + i) * HD + ch], t);
                acc[ch] += fmaxf(t, 0.f);
            }
        }
#pragma unroll
        for (int m = 1; m < 8; m <<= 1) {
#pragma unroll
            for (int ch = 0; ch < HD; ch++) acc[ch] += __shfl_xor(acc[ch], m, 64);
        }
        if (sub == 0) {
            float4* dst = reinterpret_cast<float4*>(Ah + (size_t)v * HD);
#pragma unroll
            for (int q = 0; q < 8; q++)
                dst[q] = make_float4(acc[4*q+0], acc[4*q+1], acc[4*q+2], acc[4*q+3]);
        }
    }
}

// ===========================================================================
// fv node kernel v2, CHANNEL-PARALLEL: thread = (v, ch); 3.2M threads.
// hid = relu(fvb1 + xv.fvW1[0:16] + [dg>0]bg + [dh>0]bh + Ag.Mg/dg + Ah.Mh/dh)
// PFga[v][ch] = bfv[ch] + hid . Nfv   (f_v never materialized)
// Weights in LDS (lane=ch conflict-free); Ag/Ah rows via broadcast float4.
// ===========================================================================
__global__ __launch_bounds__(256) void fv_node_kernel(
    const float* __restrict__ xv,
    const float* __restrict__ Ag, const float* __restrict__ Ah,
    const int* __restrict__ deg_g, const int* __restrict__ deg_h,
    const float* __restrict__ fvW1, const float* __restrict__ fvb1,
    const float* __restrict__ Mg, const float* __restrict__ bg,
    const float* __restrict__ Mh, const float* __restrict__ bh,
    const float* __restrict__ Nfv, const float* __restrict__ bfv,
    float* __restrict__ PFga, int nV)
{
    __shared__ float sMg[1024], sMh[1024], sN[1024], sF[512];
    __shared__ float sbg[32], sbh[32], sbf[32], sb1[32];
    for (int i = threadIdx.x; i < 1024; i += 256) {
        sMg[i] = Mg[i]; sMh[i] = Mh[i]; sN[i] = Nfv[i];
    }
    for (int i = threadIdx.x; i < 512; i += 256) sF[i] = fvW1[i];
    if (threadIdx.x < 32) {
        sbg[threadIdx.x] = bg[threadIdx.x];
        sbh[threadIdx.x] = bh[threadIdx.x];
        sbf[threadIdx.x] = bfv[threadIdx.x];
        sb1[threadIdx.x] = fvb1[threadIdx.x];
    }
    __syncthreads();

    int gid = blockIdx.x * 256 + threadIdx.x;
    int v = gid >> 5, ch = threadIdx.x & 31;
    if (v >= nV) return;

    float x = (ch < ND) ? xv[(size_t)v * ND + ch] : 0.f;
    float t = sb1[ch];
#pragma unroll
    for (int i = 0; i < ND; i++) t = fmaf(__shfl(x, i, 32), sF[i * 32 + ch], t);

    float agr[HD], ahr[HD];
    {
        const float4* pg4 = reinterpret_cast<const float4*>(Ag + (size_t)v * HD);
        const float4* ph4 = reinterpret_cast<const float4*>(Ah + (size_t)v * HD);
#pragma unroll
        for (int q = 0; q < 8; q++) {
            float4 a = pg4[q];
            agr[4*q+0] = a.x; agr[4*q+1] = a.y; agr[4*q+2] = a.z; agr[4*q+3] = a.w;
            float4 b = ph4[q];
            ahr[4*q+0] = b.x; ahr[4*q+1] = b.y; ahr[4*q+2] = b.z; ahr[4*q+3] = b.w;
        }
    }
    float sg = 0.f, sh = 0.f;
#pragma unroll
    for (int c = 0; c < HD; c++) {
        sg = fmaf(agr[c], sMg[c * 32 + ch], sg);
        sh = fmaf(ahr[c], sMh[c * 32 + ch], sh);
    }
    int dg = deg_g[v], dh = deg_h[v];
    float invg = dg > 0 ? 1.f / (float)dg : 0.f;
    float invh = dh > 0 ? 1.f / (float)dh : 0.f;
    t += (dg > 0 ? sbg[ch] : 0.f) + (dh > 0 ? sbh[ch] : 0.f) + invg * sg + invh * sh;
    float hid = fmaxf(t, 0.f);

    float pf = sbf[ch];
#pragma unroll
    for (int h = 0; h < HD; h++) pf = fmaf(__shfl(hid, h, 32), sN[h * 32 + ch], pf);
    PFga[(size_t)v * HD + ch] = pf;
}

// ===========================================================================
// ga edge kernel: one full wave (64 lanes) per cut node, lane = edge-slot.
// Per edge: acc[ch] += relu(PXga[ch] + PFga[t][ch] + ea . gaW1[48:56][ch]).
// ===========================================================================
__global__ __launch_bounds__(256, 4) void ga_edge_kernel(
    const float* __restrict__ PXga, const float* __restrict__ PFga,
    const float* __restrict__ ea_a,
    const int* __restrict__ a2v_tgt,
    const int* __restrict__ off_a, const int* __restrict__ deg_a, const int* __restrict__ csr_a,
    const float* __restrict__ gaW1,
    float* __restrict__ Aga, int nA)
{
    int gid = blockIdx.x * 256 + threadIdx.x;
    int a   = gid >> 6;
    int ln  = threadIdx.x & 63;
    if (a >= nA) return;

    float px[HD], acc[HD];
    {
        const float4* pp = reinterpret_cast<const float4*>(PXga + (size_t)a * HD);
#pragma unroll
        for (int q = 0; q < 8; q++) {
            float4 t = pp[q];
            px[4*q+0] = t.x; px[4*q+1] = t.y; px[4*q+2] = t.z; px[4*q+3] = t.w;
        }
    }
#pragma unroll
    for (int ch = 0; ch < HD; ch++) acc[ch] = 0.f;

    int base = off_a[a], d = deg_a[a];
    for (int k = ln; k < d; k += 64) {
        int e = csr_a[base + k];
        int t = a2v_tgt[e];
        float pf[HD], ev[ED];
        {
            const float4* p = reinterpret_cast<const float4*>(PFga + (size_t)t * HD);
#pragma unroll
            for (int q = 0; q < 8; q++) {
                float4 w = p[q];
                pf[4*q+0] = w.x; pf[4*q+1] = w.y; pf[4*q+2] = w.z; pf[4*q+3] = w.w;
            }
            const float4* pe = reinterpret_cast<const float4*>(ea_a + (size_t)e * ED);
            float4 q0 = pe[0], q1 = pe[1];
            ev[0]=q0.x; ev[1]=q0.y; ev[2]=q0.z; ev[3]=q0.w;
            ev[4]=q1.x; ev[5]=q1.y; ev[6]=q1.z; ev[7]=q1.w;
        }
#pragma unroll
        for (int ch = 0; ch < HD; ch++) {
            float t2 = px[ch] + pf[ch];
#pragma unroll
            for (int i = 0; i < ED; i++) t2 = fmaf(ev[i], gaW1[(ND + HD + i) * HD + ch], t2);
            acc[ch] += fmaxf(t2, 0.f);
        }
    }
#pragma unroll
    for (int m = 1; m < 64; m <<= 1) {
#pragma unroll
        for (int ch = 0; ch < HD; ch++) acc[ch] += __shfl_xor(acc[ch], m, 64);
    }
    if (ln == 0) {
        float4* dst = reinterpret_cast<float4*>(Aga + (size_t)a * HD);
#pragma unroll
        for (int q = 0; q < 8; q++)
            dst[q] = make_float4(acc[4*q+0], acc[4*q+1], acc[4*q+2], acc[4*q+3]);
    }
}

// ===========================================================================
// fa node kernel v2, CHANNEL-PARALLEL: thread = (a, ch) -> final output.
// hid = relu(fab1 + xa.faW1[0:16] + [d>0]bga + Aga.Mga/d)
// out[a][ch] = fab2[ch] + hid . faW2
// ===========================================================================
__global__ __launch_bounds__(256) void fa_node_kernel(
    const float* __restrict__ xa,
    const float* __restrict__ Aga, const int* __restrict__ deg_a,
    const float* __restrict__ faW1, const float* __restrict__ fab1,
    const float* __restrict__ faW2, const float* __restrict__ fab2,
    const float* __restrict__ Mga, const float* __restrict__ bga,
    float* __restrict__ out, int nA)
{
    __shared__ float sM[1024], sW2[1024], sF[512];
    __shared__ float sbga[32], sb1[32], sb2[32];
    for (int i = threadIdx.x; i < 1024; i += 256) { sM[i] = Mga[i]; sW2[i] = faW2[i]; }
    for (int i = threadIdx.x; i < 512; i += 256) sF[i] = faW1[i];
    if (threadIdx.x < 32) {
        sbga[threadIdx.x] = bga[threadIdx.x];
        sb1[threadIdx.x]  = fab1[threadIdx.x];
        sb2[threadIdx.x]  = fab2[threadIdx.x];
    }
    __syncthreads();

    int gid = blockIdx.x * 256 + threadIdx.x;
    int a = gid >> 5, ch = threadIdx.x & 31;
    if (a >= nA) return;

    float x = (ch < ND) ? xa[(size_t)a * ND + ch] : 0.f;
    float t = sb1[ch];
#pragma unroll
    for (int i = 0; i < ND; i++) t = fmaf(__shfl(x, i, 32), sF[i * 32 + ch], t);

    float agr[HD];
    {
        const float4* pg4 = reinterpret_cast<const float4*>(Aga + (size_t)a * HD);
#pragma unroll
        for (int q = 0; q < 8; q++) {
            float4 w = pg4[q];
            agr[4*q+0] = w.x; agr[4*q+1] = w.y; agr[4*q+2] = w.z; agr[4*q+3] = w.w;
        }
    }
    float s = 0.f;
#pragma unroll
    for (int c = 0; c < HD; c++) s = fmaf(agr[c], sM[c * 32 + ch], s);
    int d = deg_a[a];
    float inv = d > 0 ? 1.f / (float)d : 0.f;
    t += (d > 0 ? sbga[ch] : 0.f) + inv * s;
    float hid = fmaxf(t, 0.f);

    float o = sb2[ch];
#pragma unroll
    for (int h = 0; h < HD; h++) o = fmaf(__shfl(hid, h, 32), sW2[h * 32 + ch], o);
    out[(size_t)a * HD + ch] = o;
}

// ===========================================================================
extern "C" void kernel_launch(void* const* d_in, const int* in_sizes, int n_in,
                              void* d_out, int out_size, void* d_ws, size_t ws_size,
                              hipStream_t stream) {
    const float* x_c    = (const float*)d_in[0];
    const float* x_v    = (const float*)d_in[1];
    const float* x_a    = (const float*)d_in[2];
    const int*   ei_c2v = (const int*)d_in[3];
    const int*   ei_a2v = (const int*)d_in[4];
    const float* ea_c2v = (const float*)d_in[5];
    const float* ea_a2v = (const float*)d_in[6];
    const float *gv_W1=(const float*)d_in[7],  *gv_b1=(const float*)d_in[8],
                *gv_W2=(const float*)d_in[9],  *gv_b2=(const float*)d_in[10];
    const float *hv_W1=(const float*)d_in[11], *hv_b1=(const float*)d_in[12],
                *hv_W2=(const float*)d_in[13], *hv_b2=(const float*)d_in[14];
    const float *fv_W1=(const float*)d_in[15], *fv_b1=(const float*)d_in[16],
                *fv_W2=(const float*)d_in[17], *fv_b2=(const float*)d_in[18];
    const float *ga_W1=(const float*)d_in[19], *ga_b1=(const float*)d_in[20],
                *ga_W2=(const float*)d_in[21], *ga_b2=(const float*)d_in[22];
    const float *fa_W1=(const float*)d_in[23], *fa_b1=(const float*)d_in[24],
                *fa_W2=(const float*)d_in[25], *fa_b2=(const float*)d_in[26];

    const int NC = in_sizes[0] / ND;
    const int NV = in_sizes[1] / ND;
    const int NA = in_sizes[2] / ND;
    const int EC = in_sizes[3] / 2;
    const int EA = in_sizes[4] / 2;
    (void)n_in; (void)ws_size; (void)out_size;

    const int* c2v_s = ei_c2v;            // constraint side of c2v
    const int* c2v_t = ei_c2v + EC;       // variable side
    const int* a2v_s = ei_a2v;            // cut node side
    const int* a2v_t = ei_a2v + EA;       // variable side

    const int chunksV = (NV + 1023) / 1024;
    const int chunksA = (NA + 1023) / 1024;

    // Workspace layout (4B words)
    int* wsI = (int*)d_ws;
    int* deg_g = wsI;                 // NV
    int* deg_h = deg_g + NV;          // NV
    int* deg_a = deg_h + NV;          // NA
    int* off_g = deg_a + NA;          // NV
    int* off_h = off_g + NV;          // NV
    int* off_a = off_h + NV;          // NA
    int* cur_g = off_a + NA;          // NV
    int* cur_h = cur_g + NV;          // NV
    int* cur_a = cur_h + NV;          // NA
    int* csum_g = cur_a + NA;         // 1024
    int* csum_h = csum_g + 1024;      // 1024
    int* csum_a = csum_h + 1024;      // 1024
    int* csr_g = csum_a + 1024;       // EC
    int* csr_h = csr_g + EC;          // EA
    int* csr_a = csr_h + EA;          // EA
    float* PXg = (float*)(csr_a + EA);    // NV*HD  (aliased as PFga later)
    float* PXh = PXg + (size_t)NV * HD;   // NV*HD
    float* PCg = PXh + (size_t)NV * HD;   // NC*HD
    float* PAh = PCg + (size_t)NC * HD;   // NA*HD
    float* PXga= PAh + (size_t)NA * HD;   // NA*HD
    float* Ag  = PXga + (size_t)NA * HD;  // NV*HD
    float* Ah  = Ag + (size_t)NV * HD;    // NV*HD
    float* Aga = Ah + (size_t)NV * HD;    // NA*HD
    float* Mg  = Aga + (size_t)NA * HD;   // 1024
    float* Mh  = Mg + HD * HD;            // 1024
    float* Mga = Mh + HD * HD;            // 1024
    float* Nfv = Mga + HD * HD;           // 1024
    float* bgv = Nfv + HD * HD;           // 32
    float* bhv = bgv + HD;                // 32
    float* bgav= bhv + HD;                // 32
    float* bfv = bgav + HD;               // 32
    float* PFga = PXg;                    // alias: PXg dead after fv_edge

    // zero degree histograms only
    hipMemsetAsync(deg_g, 0, (size_t)(2 * NV + NA) * sizeof(int), stream);

    // channel-parallel precompute (node partials + folded matrices)
    {
        int bV = (NV * 32 + 255) / 256, bC = (NC * 32 + 255) / 256, bA = (NA * 32 + 255) / 256;
        precompB_kernel<<<bV + bC + bA + 4, 256, 0, stream>>>(
            x_v, x_c, x_a,
            gv_W1, gv_b1, hv_W1, hv_b1, ga_W1, ga_b1,
            gv_W2, gv_b2, hv_W2, hv_b2, ga_W2, ga_b2,
            fv_W1, fv_W2, fv_b2, fa_W1,
            PXg, PXh, PCg, PAh, PXga,
            Mg, bgv, Mh, bhv, Mga, bgav, Nfv, bfv, NV, NC, NA);
    }

    // histograms
    hist_kernel<<<(EC + 255) / 256, 256, 0, stream>>>(c2v_t, deg_g, EC);
    hist2_kernel<<<(EA + 255) / 256, 256, 0, stream>>>(a2v_t, deg_h, a2v_s, deg_a, EA);

    // parallel exclusive scans (fused)
    scan_p1f<<<2 * chunksV + chunksA, 256, 0, stream>>>(
        deg_g, deg_h, deg_a, csum_g, csum_h, csum_a, NV, NA, chunksV);
    scan_p2<<<3, 1024, 0, stream>>>(csum_g, chunksV, csum_h, chunksV, csum_a, chunksA);
    scan_p3f<<<2 * chunksV + chunksA, 1024, 0, stream>>>(
        deg_g, deg_h, deg_a, csum_g, csum_h, csum_a,
        off_g, off_h, off_a, cur_g, cur_h, cur_a, NV, NA, chunksV);

    // scatter edge ids into CSR
    scatter_kernel<<<(EC + 255) / 256, 256, 0, stream>>>(c2v_t, cur_g, csr_g, EC);
    scatter2_kernel<<<(EA + 255) / 256, 256, 0, stream>>>(a2v_t, cur_h, csr_h,
                                                          a2v_s, cur_a, csr_a, EA);

    // variable-node edge aggregation (8 lanes/node, precomputed partials)
    fv_edge_kernel<<<(NV * 8 + 255) / 256, 256, 0, stream>>>(
        PXg, PCg, PXh, PAh, c2v_s, a2v_s, ea_c2v, ea_a2v,
        off_g, deg_g, csr_g, off_h, deg_h, csr_h,
        gv_W1, hv_W1, Ag, Ah, NV);

    // variable-node MLP -> PFga (channel-parallel; f_v folded into ga partial)
    fv_node_kernel<<<(NV * 32 + 255) / 256, 256, 0, stream>>>(
        x_v, Ag, Ah, deg_g, deg_h,
        fv_W1, fv_b1, Mg, bgv, Mh, bhv, Nfv, bfv, PFga, NV);

    // cut-node edge aggregation (64 lanes/node)
    ga_edge_kernel<<<(NA * 64 + 255) / 256, 256, 0, stream>>>(
        PXga, PFga, ea_a2v, a2v_t,
        off_a, deg_a, csr_a, ga_W1, Aga, NA);

    // cut-node MLP -> output (channel-parallel)
    fa_node_kernel<<<(NA * 32 + 255) / 256, 256, 0, stream>>>(
        x_a, Aga, deg_a,
        fa_W1, fa_b1, fa_W2, fa_b2, Mga, bgav, (float*)d_out, NA);
}

// Round 7
// 615.483 us; speedup vs baseline: 2.2599x; 1.1152x over previous
//
#include <hip/hip_runtime.h>

#define HD 32   // hidden/emb dim
#define ND 16   // node feature dim
#define ED 8    // edge feature dim

// ===========================================================================
// CSR build: fused histogram -> parallel 3-pass exclusive scan -> fused scatter
// ===========================================================================
__global__ __launch_bounds__(256) void histF_kernel(
    const int* __restrict__ c2v_t, int* __restrict__ deg_g, int nEC, int bEC,
    const int* __restrict__ a2v_t, int* __restrict__ deg_h,
    const int* __restrict__ a2v_s, int* __restrict__ deg_a, int nEA)
{
    int b = blockIdx.x;
    if (b < bEC) {
        int i = b * 256 + threadIdx.x;
        if (i < nEC) atomicAdd(&deg_g[c2v_t[i]], 1);
    } else {
        int i = (b - bEC) * 256 + threadIdx.x;
        if (i < nEA) { atomicAdd(&deg_h[a2v_t[i]], 1); atomicAdd(&deg_a[a2v_s[i]], 1); }
    }
}

// pass 1 (fused over 3 arrays): per-1024-chunk sums
__global__ __launch_bounds__(256) void scan_p1f(
    const int* __restrict__ dg, const int* __restrict__ dh, const int* __restrict__ da,
    int* __restrict__ cg, int* __restrict__ chs, int* __restrict__ ca,
    int nV, int nA, int chunksV)
{
    int b = blockIdx.x;
    const int* in; int* cs; int n; int c;
    if (b < chunksV)            { in = dg; cs = cg;  n = nV; c = b; }
    else if (b < 2 * chunksV)   { in = dh; cs = chs; n = nV; c = b - chunksV; }
    else                        { in = da; cs = ca;  n = nA; c = b - 2 * chunksV; }

    int i0 = c * 1024 + threadIdx.x * 4;
    int s = 0;
#pragma unroll
    for (int j = 0; j < 4; j++) { int i = i0 + j; if (i < n) s += in[i]; }
#pragma unroll
    for (int m = 1; m < 64; m <<= 1) s += __shfl_xor(s, m, 64);
    __shared__ int ws[4];
    if ((threadIdx.x & 63) == 0) ws[threadIdx.x >> 6] = s;
    __syncthreads();
    if (threadIdx.x == 0) cs[c] = ws[0] + ws[1] + ws[2] + ws[3];
}

// pass 2: exclusive scan of chunk sums in place (n <= 1024), 3 arrays
__device__ __forceinline__ void exscan_block(int* __restrict__ c, int n)
{
    int i = threadIdx.x;
    int v = (i < n) ? c[i] : 0;
    int x = v;
    int lane = i & 63, wid = i >> 6;
#pragma unroll
    for (int dd = 1; dd < 64; dd <<= 1) {
        int y = __shfl_up(x, dd, 64);
        if (lane >= dd) x += y;
    }
    __shared__ int ws[16];
    if (lane == 63) ws[wid] = x;
    __syncthreads();
    if (i == 0) {
        int a = 0;
#pragma unroll
        for (int w = 0; w < 16; w++) { int t = ws[w]; ws[w] = a; a += t; }
    }
    __syncthreads();
    int excl = ws[wid] + x - v;
    if (i < n) c[i] = excl;
}

__global__ __launch_bounds__(1024) void scan_p2(
    int* c0, int n0, int* c1, int n1, int* c2, int n2)
{
    if (blockIdx.x == 0)      exscan_block(c0, n0);
    else if (blockIdx.x == 1) exscan_block(c1, n1);
    else                      exscan_block(c2, n2);
}

// pass 3 (fused): per-chunk exclusive prefix + chunk base -> off, cur
__global__ __launch_bounds__(1024) void scan_p3f(
    const int* __restrict__ dg, const int* __restrict__ dh, const int* __restrict__ da,
    const int* __restrict__ cg, const int* __restrict__ chs, const int* __restrict__ ca,
    int* __restrict__ og, int* __restrict__ oh, int* __restrict__ oa,
    int* __restrict__ ug, int* __restrict__ uh, int* __restrict__ ua,
    int nV, int nA, int chunksV)
{
    int b = blockIdx.x;
    const int* deg; const int* cbase; int* off; int* cur; int n; int c;
    if (b < chunksV)          { deg = dg; cbase = cg;  off = og; cur = ug; n = nV; c = b; }
    else if (b < 2 * chunksV) { deg = dh; cbase = chs; off = oh; cur = uh; n = nV; c = b - chunksV; }
    else                      { deg = da; cbase = ca;  off = oa; cur = ua; n = nA; c = b - 2 * chunksV; }

    int i = c * 1024 + threadIdx.x;
    int v = (i < n) ? deg[i] : 0;
    int x = v;
    int lane = threadIdx.x & 63, wid = threadIdx.x >> 6;
#pragma unroll
    for (int dd = 1; dd < 64; dd <<= 1) {
        int y = __shfl_up(x, dd, 64);
        if (lane >= dd) x += y;
    }
    __shared__ int ws[16];
    if (lane == 63) ws[wid] = x;
    __syncthreads();
    if (threadIdx.x == 0) {
        int a = 0;
#pragma unroll
        for (int w = 0; w < 16; w++) { int t = ws[w]; ws[w] = a; a += t; }
    }
    __syncthreads();
    int excl = cbase[c] + ws[wid] + x - v;
    if (i < n) { off[i] = excl; cur[i] = excl; }
}

// Fused scatter. SORTED: write src/tgt id + edge-attr payload into sorted slot.
// Fallback: write edge id only (round-6 behavior).
template<bool SORTED>
__global__ __launch_bounds__(256) void scatterF_kernel(
    const int* __restrict__ c2v_s, const int* __restrict__ c2v_t,
    const float* __restrict__ ea_c,
    int* __restrict__ cur_g, int* __restrict__ idx_g, float* __restrict__ eag,
    int nEC, int bEC,
    const int* __restrict__ a2v_s, const int* __restrict__ a2v_t,
    const float* __restrict__ ea_a,
    int* __restrict__ cur_h, int* __restrict__ idx_h, float* __restrict__ eah,
    int* __restrict__ cur_a, int* __restrict__ idx_a, float* __restrict__ eaa,
    int nEA)
{
    int b = blockIdx.x;
    if (b < bEC) {
        int i = b * 256 + threadIdx.x;
        if (i >= nEC) return;
        int t = c2v_t[i];
        int p = atomicAdd(&cur_g[t], 1);
        if (SORTED) {
            idx_g[p] = c2v_s[i];
            const float4* pe = reinterpret_cast<const float4*>(ea_c + (size_t)i * ED);
            float4 e0 = pe[0], e1 = pe[1];
            float4* d = reinterpret_cast<float4*>(eag + (size_t)p * ED);
            d[0] = e0; d[1] = e1;
        } else {
            idx_g[p] = i;
        }
    } else {
        int i = (b - bEC) * 256 + threadIdx.x;
        if (i >= nEA) return;
        int s = a2v_s[i], t = a2v_t[i];
        int p = atomicAdd(&cur_h[t], 1);
        int q = atomicAdd(&cur_a[s], 1);
        if (SORTED) {
            const float4* pe = reinterpret_cast<const float4*>(ea_a + (size_t)i * ED);
            float4 e0 = pe[0], e1 = pe[1];
            idx_h[p] = s;
            float4* dh = reinterpret_cast<float4*>(eah + (size_t)p * ED);
            dh[0] = e0; dh[1] = e1;
            idx_a[q] = t;
            float4* da = reinterpret_cast<float4*>(eaa + (size_t)q * ED);
            da[0] = e0; da[1] = e1;
        } else {
            idx_h[p] = i;
            idx_a[q] = i;
        }
    }
}

// ===========================================================================
// Channel-parallel precompute. thread = (node, ch). Weights staged in LDS.
//  PXg[v][ch]=gvb1+xv.gvW1[0:16]    PXh[v][ch]=hvb1+xv.hvW1[0:16]
//  PCg[c][ch]=xc.gvW1[16:32]        PAh[a][ch]=xa.hvW1[16:32]
//  PXga[a][ch]=gab1+xa.gaW1[0:16]
// Plus folded matrices (last 4 blocks):
//  Mg=gvW2@fvW1[16:48], bg; Mh,bh (rows 48:80); Mga=gaW2@faW1[16:48], bga;
//  Nfv=fvW2@gaW1[16:48], bfv=fvb2@gaW1[16:48]
// ===========================================================================
__global__ __launch_bounds__(256) void precompB_kernel(
    const float* __restrict__ xv, const float* __restrict__ xc, const float* __restrict__ xa,
    const float* __restrict__ gvW1, const float* __restrict__ gvb1,
    const float* __restrict__ hvW1, const float* __restrict__ hvb1,
    const float* __restrict__ gaW1, const float* __restrict__ gab1,
    const float* __restrict__ gvW2, const float* __restrict__ gvb2,
    const float* __restrict__ hvW2, const float* __restrict__ hvb2,
    const float* __restrict__ gaW2, const float* __restrict__ gab2,
    const float* __restrict__ fvW1, const float* __restrict__ fvW2,
    const float* __restrict__ fvb2, const float* __restrict__ faW1,
    float* __restrict__ PXg, float* __restrict__ PXh,
    float* __restrict__ PCg, float* __restrict__ PAh, float* __restrict__ PXga,
    float* __restrict__ Mg, float* __restrict__ bg,
    float* __restrict__ Mh, float* __restrict__ bh,
    float* __restrict__ Mga, float* __restrict__ bga,
    float* __restrict__ Nfv, float* __restrict__ bfv,
    int nV, int nC, int nA)
{
    int bV = (nV * 32 + 255) / 256, bC = (nC * 32 + 255) / 256, bA = (nA * 32 + 255) / 256;
    int b = blockIdx.x;
    int ch = threadIdx.x & 31;
    __shared__ float s0[512], s1[512];

    if (b < bV) {
        for (int i = threadIdx.x; i < 512; i += 256) { s0[i] = gvW1[i]; s1[i] = hvW1[i]; }
        __syncthreads();
        int v = (b * 256 + (int)threadIdx.x) >> 5;
        if (v >= nV) return;
        float x = (ch < ND) ? xv[(size_t)v * ND + ch] : 0.f;
        float pg = gvb1[ch], ph = hvb1[ch];
#pragma unroll
        for (int i = 0; i < ND; i++) {
            float xi = __shfl(x, i, 32);
            pg = fmaf(xi, s0[i * 32 + ch], pg);
            ph = fmaf(xi, s1[i * 32 + ch], ph);
        }
        PXg[(size_t)v * 32 + ch] = pg;
        PXh[(size_t)v * 32 + ch] = ph;
    } else if (b < bV + bC) {
        for (int i = threadIdx.x; i < 512; i += 256) s0[i] = gvW1[512 + i];
        __syncthreads();
        int c = ((b - bV) * 256 + (int)threadIdx.x) >> 5;
        if (c >= nC) return;
        float x = (ch < ND) ? xc[(size_t)c * ND + ch] : 0.f;
        float p = 0.f;
#pragma unroll
        for (int i = 0; i < ND; i++) p = fmaf(__shfl(x, i, 32), s0[i * 32 + ch], p);
        PCg[(size_t)c * 32 + ch] = p;
    } else if (b < bV + bC + bA) {
        for (int i = threadIdx.x; i < 512; i += 256) { s0[i] = hvW1[512 + i]; s1[i] = gaW1[i]; }
        __syncthreads();
        int a = ((b - bV - bC) * 256 + (int)threadIdx.x) >> 5;
        if (a >= nA) return;
        float x = (ch < ND) ? xa[(size_t)a * ND + ch] : 0.f;
        float ph = 0.f, pg = gab1[ch];
#pragma unroll
        for (int i = 0; i < ND; i++) {
            float xi = __shfl(x, i, 32);
            ph = fmaf(xi, s0[i * 32 + ch], ph);
            pg = fmaf(xi, s1[i * 32 + ch], pg);
        }
        PAh[(size_t)a * 32 + ch] = ph;
        PXga[(size_t)a * 32 + ch] = pg;
    } else {
        int m = b - (bV + bC + bA);
        const float *W2, *b2, *T; float *M, *bb; int toff;
        if (m == 0)      { W2 = gvW2; b2 = gvb2; T = fvW1; toff = ND;      M = Mg;  bb = bg;  }
        else if (m == 1) { W2 = hvW2; b2 = hvb2; T = fvW1; toff = ND + HD; M = Mh;  bb = bh;  }
        else if (m == 2) { W2 = gaW2; b2 = gab2; T = faW1; toff = ND;      M = Mga; bb = bga; }
        else             { W2 = fvW2; b2 = fvb2; T = gaW1; toff = ND;      M = Nfv; bb = bfv; }
        for (int idx = threadIdx.x; idx < 1024; idx += 256) {
            int c = idx >> 5, h = idx & 31;
            float s = 0.f;
#pragma unroll
            for (int o = 0; o < HD; o++) s = fmaf(W2[c * HD + o], T[(toff + o) * HD + h], s);
            M[idx] = s;
        }
        if (threadIdx.x < HD) {
            int h = threadIdx.x;
            float s = 0.f;
#pragma unroll
            for (int o = 0; o < HD; o++) s = fmaf(b2[o], T[(toff + o) * HD + h], s);
            bb[h] = s;
        }
    }
}

// ===========================================================================
// fv edge kernel: 8 lanes per variable node, lane = edge-slot.
// Per edge: acc[ch] += relu(PXg[ch] + PCg[s][ch] + ea . W[32:40][ch]).
// SORTED: src id + ea read as coalesced sorted streams (no gather via edge id).
// ===========================================================================
template<bool SORTED>
__global__ __launch_bounds__(256) void fv_edge_kernel(
    const float* __restrict__ PXg, const float* __restrict__ PCg,
    const float* __restrict__ PXh, const float* __restrict__ PAh,
    const int* __restrict__ idx_g, const float* __restrict__ eag,
    const int* __restrict__ idx_h, const float* __restrict__ eah,
    const int* __restrict__ c2v_src, const int* __restrict__ a2v_src,
    const float* __restrict__ ea_c, const float* __restrict__ ea_a,
    const int* __restrict__ off_g, const int* __restrict__ deg_g,
    const int* __restrict__ off_h, const int* __restrict__ deg_h,
    const float* __restrict__ gvW1, const float* __restrict__ hvW1,
    float* __restrict__ Ag, float* __restrict__ Ah, int nV)
{
    int gid = blockIdx.x * 256 + threadIdx.x;
    int v   = gid >> 3;
    int sub = threadIdx.x & 7;
    if (v >= nV) return;

    float px[HD], acc[HD];

    // ---------------- g: c2v edges ----------------
    {
        const float4* pp = reinterpret_cast<const float4*>(PXg + (size_t)v * HD);
#pragma unroll
        for (int q = 0; q < 8; q++) {
            float4 t = pp[q];
            px[4*q+0] = t.x; px[4*q+1] = t.y; px[4*q+2] = t.z; px[4*q+3] = t.w;
        }
#pragma unroll
        for (int ch = 0; ch < HD; ch++) acc[ch] = 0.f;

        int base = off_g[v], d = deg_g[v];
        for (int k = sub; k < d; k += 8) {
            int slot = base + k;
            int s; const float4* pe;
            if (SORTED) {
                s = idx_g[slot];
                pe = reinterpret_cast<const float4*>(eag + (size_t)slot * ED);
            } else {
                int e = idx_g[slot];
                s = c2v_src[e];
                pe = reinterpret_cast<const float4*>(ea_c + (size_t)e * ED);
            }
            float pc[HD], ev[ED];
            {
                const float4* p = reinterpret_cast<const float4*>(PCg + (size_t)s * HD);
#pragma unroll
                for (int q = 0; q < 8; q++) {
                    float4 t = p[q];
                    pc[4*q+0] = t.x; pc[4*q+1] = t.y; pc[4*q+2] = t.z; pc[4*q+3] = t.w;
                }
                float4 q0 = pe[0], q1 = pe[1];
                ev[0]=q0.x; ev[1]=q0.y; ev[2]=q0.z; ev[3]=q0.w;
                ev[4]=q1.x; ev[5]=q1.y; ev[6]=q1.z; ev[7]=q1.w;
            }
#pragma unroll
            for (int ch = 0; ch < HD; ch++) {
                float t = px[ch] + pc[ch];
#pragma unroll
                for (int i = 0; i < ED; i++) t = fmaf(ev[i], gvW1[(2 * ND + i) * HD + ch], t);
                acc[ch] += fmaxf(t, 0.f);
            }
        }
#pragma unroll
        for (int m = 1; m < 8; m <<= 1) {
#pragma unroll
            for (int ch = 0; ch < HD; ch++) acc[ch] += __shfl_xor(acc[ch], m, 64);
        }
        if (sub == 0) {
            float4* dst = reinterpret_cast<float4*>(Ag + (size_t)v * HD);
#pragma unroll
            for (int q = 0; q < 8; q++)
                dst[q] = make_float4(acc[4*q+0], acc[4*q+1], acc[4*q+2], acc[4*q+3]);
        }
    }

    // ---------------- h: a2v edges ----------------
    {
        const float4* pp = reinterpret_cast<const float4*>(PXh + (size_t)v * HD);
#pragma unroll
        for (int q = 0; q < 8; q++) {
            float4 t = pp[q];
            px[4*q+0] = t.x; px[4*q+1] = t.y; px[4*q+2] = t.z; px[4*q+3] = t.w;
        }
#pragma unroll
        for (int ch = 0; ch < HD; ch++) acc[ch] = 0.f;

        int base = off_h[v], d = deg_h[v];
        for (int k = sub; k < d; k += 8) {
            int slot = base + k;
            int s; const float4* pe;
            if (SORTED) {
                s = idx_h[slot];
                pe = reinterpret_cast<const float4*>(eah + (size_t)slot * ED);
            } else {
                int e = idx_h[slot];
                s = a2v_src[e];
                pe = reinterpret_cast<const float4*>(ea_a + (size_t)e * ED);
            }
            float pc[HD], ev[ED];
            {
                const float4* p = reinterpret_cast<const float4*>(PAh + (size_t)s * HD);
#pragma unroll
                for (int q = 0; q < 8; q++) {
                    float4 t = p[q];
                    pc[4*q+0] = t.x; pc[4*q+1] = t.y; pc[4*q+2] = t.z; pc[4*q+3] = t.w;
                }
                float4 q0 = pe[0], q1 = pe[1];
                ev[0]=q0.x; ev[1]=q0.y; ev[2]=q0.z; ev[3]=q0.w;
                ev[4]=q1.x; ev[5]=q1.y; ev[6]=q1.z; ev[7]=q1.w;
            }
#pragma unroll
            for (int ch = 0; ch < HD; ch++) {
                float t = px[ch] + pc[ch];
#pragma unroll
                for (int i = 0; i < ED; i++) t = fmaf(ev[i], hvW1[(2 * ND + i) * HD + ch], t);
                acc[ch] += fmaxf(t, 0.f);
            }
        }
#pragma unroll
        for (int m = 1; m < 8; m <<= 1) {
#pragma unroll
            for (int ch = 0; ch < HD; ch++) acc[ch] += __shfl_xor(acc[ch], m, 64);
        }
        if (sub == 0) {
            float4* dst = reinterpret_cast<float4*>(Ah + (size_t)v * HD);
#pragma unroll
            for (int q = 0; q < 8; q++)
                dst[q] = make_float4(acc[4*q+0], acc[4*q+1], acc[4*q+2], acc[4*q+3]);
        }
    }
}

// ===========================================================================
// fv node kernel, CHANNEL-PARALLEL: thread = (v, ch).
// hid = relu(fvb1 + xv.fvW1[0:16] + [dg>0]bg + [dh>0]bh + Ag.Mg/dg + Ah.Mh/dh)
// PFga[v][ch] = bfv[ch] + hid . Nfv   (f_v never materialized)
// ===========================================================================
__global__ __launch_bounds__(256) void fv_node_kernel(
    const float* __restrict__ xv,
    const float* __restrict__ Ag, const float* __restrict__ Ah,
    const int* __restrict__ deg_g, const int* __restrict__ deg_h,
    const float* __restrict__ fvW1, const float* __restrict__ fvb1,
    const float* __restrict__ Mg, const float* __restrict__ bg,
    const float* __restrict__ Mh, const float* __restrict__ bh,
    const float* __restrict__ Nfv, const float* __restrict__ bfv,
    float* __restrict__ PFga, int nV)
{
    __shared__ float sMg[1024], sMh[1024], sN[1024], sF[512];
    __shared__ float sbg[32], sbh[32], sbf[32], sb1[32];
    for (int i = threadIdx.x; i < 1024; i += 256) {
        sMg[i] = Mg[i]; sMh[i] = Mh[i]; sN[i] = Nfv[i];
    }
    for (int i = threadIdx.x; i < 512; i += 256) sF[i] = fvW1[i];
    if (threadIdx.x < 32) {
        sbg[threadIdx.x] = bg[threadIdx.x];
        sbh[threadIdx.x] = bh[threadIdx.x];
        sbf[threadIdx.x] = bfv[threadIdx.x];
        sb1[threadIdx.x] = fvb1[threadIdx.x];
    }
    __syncthreads();

    int gid = blockIdx.x * 256 + threadIdx.x;
    int v = gid >> 5, ch = threadIdx.x & 31;
    if (v >= nV) return;

    float x = (ch < ND) ? xv[(size_t)v * ND + ch] : 0.f;
    float t = sb1[ch];
#pragma unroll
    for (int i = 0; i < ND; i++) t = fmaf(__shfl(x, i, 32), sF[i * 32 + ch], t);

    float agr[HD], ahr[HD];
    {
        const float4* pg4 = reinterpret_cast<const float4*>(Ag + (size_t)v * HD);
        const float4* ph4 = reinterpret_cast<const float4*>(Ah + (size_t)v * HD);
#pragma unroll
        for (int q = 0; q < 8; q++) {
            float4 a = pg4[q];
            agr[4*q+0] = a.x; agr[4*q+1] = a.y; agr[4*q+2] = a.z; agr[4*q+3] = a.w;
            float4 b = ph4[q];
            ahr[4*q+0] = b.x; ahr[4*q+1] = b.y; ahr[4*q+2] = b.z; ahr[4*q+3] = b.w;
        }
    }
    float sg = 0.f, sh = 0.f;
#pragma unroll
    for (int c = 0; c < HD; c++) {
        sg = fmaf(agr[c], sMg[c * 32 + ch], sg);
        sh = fmaf(ahr[c], sMh[c * 32 + ch], sh);
    }
    int dg = deg_g[v], dh = deg_h[v];
    float invg = dg > 0 ? 1.f / (float)dg : 0.f;
    float invh = dh > 0 ? 1.f / (float)dh : 0.f;
    t += (dg > 0 ? sbg[ch] : 0.f) + (dh > 0 ? sbh[ch] : 0.f) + invg * sg + invh * sh;
    float hid = fmaxf(t, 0.f);

    float pf = sbf[ch];
#pragma unroll
    for (int h = 0; h < HD; h++) pf = fmaf(__shfl(hid, h, 32), sN[h * 32 + ch], pf);
    PFga[(size_t)v * HD + ch] = pf;
}

// ===========================================================================
// ga edge kernel: one full wave (64 lanes) per cut node, lane = edge-slot.
// Per edge: acc[ch] += relu(PXga[ch] + PFga[t][ch] + ea . gaW1[48:56][ch]).
// SORTED: tgt id + ea as coalesced sorted streams.
// ===========================================================================
template<bool SORTED>
__global__ __launch_bounds__(256) void ga_edge_kernel(
    const float* __restrict__ PXga, const float* __restrict__ PFga,
    const int* __restrict__ idx_a, const float* __restrict__ eaa,
    const int* __restrict__ a2v_tgt, const float* __restrict__ ea_a,
    const int* __restrict__ off_a, const int* __restrict__ deg_a,
    const float* __restrict__ gaW1,
    float* __restrict__ Aga, int nA)
{
    int gid = blockIdx.x * 256 + threadIdx.x;
    int a   = gid >> 6;
    int ln  = threadIdx.x & 63;
    if (a >= nA) return;

    float px[HD], acc[HD];
    {
        const float4* pp = reinterpret_cast<const float4*>(PXga + (size_t)a * HD);
#pragma unroll
        for (int q = 0; q < 8; q++) {
            float4 t = pp[q];
            px[4*q+0] = t.x; px[4*q+1] = t.y; px[4*q+2] = t.z; px[4*q+3] = t.w;
        }
    }
#pragma unroll
    for (int ch = 0; ch < HD; ch++) acc[ch] = 0.f;

    int base = off_a[a], d = deg_a[a];
    for (int k = ln; k < d; k += 64) {
        int slot = base + k;
        int t; const float4* pe;
        if (SORTED) {
            t = idx_a[slot];
            pe = reinterpret_cast<const float4*>(eaa + (size_t)slot * ED);
        } else {
            int e = idx_a[slot];
            t = a2v_tgt[e];
            pe = reinterpret_cast<const float4*>(ea_a + (size_t)e * ED);
        }
        float pf[HD], ev[ED];
        {
            const float4* p = reinterpret_cast<const float4*>(PFga + (size_t)t * HD);
#pragma unroll
            for (int q = 0; q < 8; q++) {
                float4 w = p[q];
                pf[4*q+0] = w.x; pf[4*q+1] = w.y; pf[4*q+2] = w.z; pf[4*q+3] = w.w;
            }
            float4 q0 = pe[0], q1 = pe[1];
            ev[0]=q0.x; ev[1]=q0.y; ev[2]=q0.z; ev[3]=q0.w;
            ev[4]=q1.x; ev[5]=q1.y; ev[6]=q1.z; ev[7]=q1.w;
        }
#pragma unroll
        for (int ch = 0; ch < HD; ch++) {
            float t2 = px[ch] + pf[ch];
#pragma unroll
            for (int i = 0; i < ED; i++) t2 = fmaf(ev[i], gaW1[(ND + HD + i) * HD + ch], t2);
            acc[ch] += fmaxf(t2, 0.f);
        }
    }
#pragma unroll
    for (int m = 1; m < 64; m <<= 1) {
#pragma unroll
        for (int ch = 0; ch < HD; ch++) acc[ch] += __shfl_xor(acc[ch], m, 64);
    }
    if (ln == 0) {
        float4* dst = reinterpret_cast<float4*>(Aga + (size_t)a * HD);
#pragma unroll
        for (int q = 0; q < 8; q++)
            dst[q] = make_float4(acc[4*q+0], acc[4*q+1], acc[4*q+2], acc[4*q+3]);
    }
}

// ===========================================================================
// fa node kernel, CHANNEL-PARALLEL: thread = (a, ch) -> final output.
// ===========================================================================
__global__ __launch_bounds__(256) void fa_node_kernel(
    const float* __restrict__ xa,
    const float* __restrict__ Aga, const int* __restrict__ deg_a,
    const float* __restrict__ faW1, const float* __restrict__ fab1,
    const float* __restrict__ faW2, const float* __restrict__ fab2,
    const float* __restrict__ Mga, const float* __restrict__ bga,
    float* __restrict__ out, int nA)
{
    __shared__ float sM[1024], sW2[1024], sF[512];
    __shared__ float sbga[32], sb1[32], sb2[32];
    for (int i = threadIdx.x; i < 1024; i += 256) { sM[i] = Mga[i]; sW2[i] = faW2[i]; }
    for (int i = threadIdx.x; i < 512; i += 256) sF[i] = faW1[i];
    if (threadIdx.x < 32) {
        sbga[threadIdx.x] = bga[threadIdx.x];
        sb1[threadIdx.x]  = fab1[threadIdx.x];
        sb2[threadIdx.x]  = fab2[threadIdx.x];
    }
    __syncthreads();

    int gid = blockIdx.x * 256 + threadIdx.x;
    int a = gid >> 5, ch = threadIdx.x & 31;
    if (a >= nA) return;

    float x = (ch < ND) ? xa[(size_t)a * ND + ch] : 0.f;
    float t = sb1[ch];
#pragma unroll
    for (int i = 0; i < ND; i++) t = fmaf(__shfl(x, i, 32), sF[i * 32 + ch], t);

    float agr[HD];
    {
        const float4* pg4 = reinterpret_cast<const float4*>(Aga + (size_t)a * HD);
#pragma unroll
        for (int q = 0; q < 8; q++) {
            float4 w = pg4[q];
            agr[4*q+0] = w.x; agr[4*q+1] = w.y; agr[4*q+2] = w.z; agr[4*q+3] = w.w;
        }
    }
    float s = 0.f;
#pragma unroll
    for (int c = 0; c < HD; c++) s = fmaf(agr[c], sM[c * 32 + ch], s);
    int d = deg_a[a];
    float inv = d > 0 ? 1.f / (float)d : 0.f;
    t += (d > 0 ? sbga[ch] : 0.f) + inv * s;
    float hid = fmaxf(t, 0.f);

    float o = sb2[ch];
#pragma unroll
    for (int h = 0; h < HD; h++) o = fmaf(__shfl(hid, h, 32), sW2[h * 32 + ch], o);
    out[(size_t)a * HD + ch] = o;
}

// ===========================================================================
extern "C" void kernel_launch(void* const* d_in, const int* in_sizes, int n_in,
                              void* d_out, int out_size, void* d_ws, size_t ws_size,
                              hipStream_t stream) {
    const float* x_c    = (const float*)d_in[0];
    const float* x_v    = (const float*)d_in[1];
    const float* x_a    = (const float*)d_in[2];
    const int*   ei_c2v = (const int*)d_in[3];
    const int*   ei_a2v = (const int*)d_in[4];
    const float* ea_c2v = (const float*)d_in[5];
    const float* ea_a2v = (const float*)d_in[6];
    const float *gv_W1=(const float*)d_in[7],  *gv_b1=(const float*)d_in[8],
                *gv_W2=(const float*)d_in[9],  *gv_b2=(const float*)d_in[10];
    const float *hv_W1=(const float*)d_in[11], *hv_b1=(const float*)d_in[12],
                *hv_W2=(const float*)d_in[13], *hv_b2=(const float*)d_in[14];
    const float *fv_W1=(const float*)d_in[15], *fv_b1=(const float*)d_in[16],
                *fv_W2=(const float*)d_in[17], *fv_b2=(const float*)d_in[18];
    const float *ga_W1=(const float*)d_in[19], *ga_b1=(const float*)d_in[20],
                *ga_W2=(const float*)d_in[21], *ga_b2=(const float*)d_in[22];
    const float *fa_W1=(const float*)d_in[23], *fa_b1=(const float*)d_in[24],
                *fa_W2=(const float*)d_in[25], *fa_b2=(const float*)d_in[26];

    const int NC = in_sizes[0] / ND;
    const int NV = in_sizes[1] / ND;
    const int NA = in_sizes[2] / ND;
    const int EC = in_sizes[3] / 2;
    const int EA = in_sizes[4] / 2;
    (void)n_in; (void)out_size;

    const int* c2v_s = ei_c2v;            // constraint side of c2v
    const int* c2v_t = ei_c2v + EC;       // variable side
    const int* a2v_s = ei_a2v;            // cut node side
    const int* a2v_t = ei_a2v + EA;       // variable side

    const int chunksV = (NV + 1023) / 1024;
    const int chunksA = (NA + 1023) / 1024;

    // Workspace layout (4B words)
    int* wsI = (int*)d_ws;
    int* deg_g = wsI;                 // NV
    int* deg_h = deg_g + NV;          // NV
    int* deg_a = deg_h + NV;          // NA
    int* off_g = deg_a + NA;          // NV
    int* off_h = off_g + NV;          // NV
    int* off_a = off_h + NV;          // NA
    int* cur_g = off_a + NA;          // NV
    int* cur_h = cur_g + NV;          // NV
    int* cur_a = cur_h + NV;          // NA
    int* csum_g = cur_a + NA;         // 1024
    int* csum_h = csum_g + 1024;      // 1024
    int* csum_a = csum_h + 1024;      // 1024
    int* idx_g = csum_a + 1024;       // EC
    int* idx_h = idx_g + EC;          // EA
    int* idx_a = idx_h + EA;          // EA
    float* PXg = (float*)(idx_a + EA);    // NV*HD  (aliased as PFga later)
    float* PXh = PXg + (size_t)NV * HD;   // NV*HD
    float* PCg = PXh + (size_t)NV * HD;   // NC*HD
    float* PAh = PCg + (size_t)NC * HD;   // NA*HD
    float* PXga= PAh + (size_t)NA * HD;   // NA*HD
    float* Ag  = PXga + (size_t)NA * HD;  // NV*HD
    float* Ah  = Ag + (size_t)NV * HD;    // NV*HD
    float* Aga = Ah + (size_t)NV * HD;    // NA*HD
    float* Mg  = Aga + (size_t)NA * HD;   // 1024
    float* Mh  = Mg + HD * HD;            // 1024
    float* Mga = Mh + HD * HD;            // 1024
    float* Nfv = Mga + HD * HD;           // 1024
    float* bgv = Nfv + HD * HD;           // 32
    float* bhv = bgv + HD;                // 32
    float* bgav= bhv + HD;                // 32
    float* bfv = bgav + HD;               // 32
    float* eag = bfv + HD;                // EC*ED  (sorted payloads, optional)
    float* eah = eag + (size_t)EC * ED;   // EA*ED
    float* eaa = eah + (size_t)EA * ED;   // EA*ED
    float* PFga = PXg;                    // alias: PXg dead after fv_edge

    size_t words_needed_sorted = (size_t)(eaa + (size_t)EA * ED - (float*)d_ws);
    bool sorted = ws_size >= words_needed_sorted * sizeof(float);

    // zero degree histograms only
    hipMemsetAsync(deg_g, 0, (size_t)(2 * NV + NA) * sizeof(int), stream);

    // channel-parallel precompute (node partials + folded matrices)
    {
        int bV = (NV * 32 + 255) / 256, bC = (NC * 32 + 255) / 256, bA = (NA * 32 + 255) / 256;
        precompB_kernel<<<bV + bC + bA + 4, 256, 0, stream>>>(
            x_v, x_c, x_a,
            gv_W1, gv_b1, hv_W1, hv_b1, ga_W1, ga_b1,
            gv_W2, gv_b2, hv_W2, hv_b2, ga_W2, ga_b2,
            fv_W1, fv_W2, fv_b2, fa_W1,
            PXg, PXh, PCg, PAh, PXga,
            Mg, bgv, Mh, bhv, Mga, bgav, Nfv, bfv, NV, NC, NA);
    }

    // fused histograms
    int bEC = (EC + 255) / 256, bEA = (EA + 255) / 256;
    histF_kernel<<<bEC + bEA, 256, 0, stream>>>(
        c2v_t, deg_g, EC, bEC, a2v_t, deg_h, a2v_s, deg_a, EA);

    // parallel exclusive scans (fused)
    scan_p1f<<<2 * chunksV + chunksA, 256, 0, stream>>>(
        deg_g, deg_h, deg_a, csum_g, csum_h, csum_a, NV, NA, chunksV);
    scan_p2<<<3, 1024, 0, stream>>>(csum_g, chunksV, csum_h, chunksV, csum_a, chunksA);
    scan_p3f<<<2 * chunksV + chunksA, 1024, 0, stream>>>(
        deg_g, deg_h, deg_a, csum_g, csum_h, csum_a,
        off_g, off_h, off_a, cur_g, cur_h, cur_a, NV, NA, chunksV);

    // fused scatter (payload-sorting if workspace permits)
    if (sorted) {
        scatterF_kernel<true><<<bEC + bEA, 256, 0, stream>>>(
            c2v_s, c2v_t, ea_c2v, cur_g, idx_g, eag, EC, bEC,
            a2v_s, a2v_t, ea_a2v, cur_h, idx_h, eah, cur_a, idx_a, eaa, EA);
        fv_edge_kernel<true><<<(NV * 8 + 255) / 256, 256, 0, stream>>>(
            PXg, PCg, PXh, PAh, idx_g, eag, idx_h, eah,
            c2v_s, a2v_s, ea_c2v, ea_a2v,
            off_g, deg_g, off_h, deg_h, gv_W1, hv_W1, Ag, Ah, NV);
    } else {
        scatterF_kernel<false><<<bEC + bEA, 256, 0, stream>>>(
            c2v_s, c2v_t, ea_c2v, cur_g, idx_g, eag, EC, bEC,
            a2v_s, a2v_t, ea_a2v, cur_h, idx_h, eah, cur_a, idx_a, eaa, EA);
        fv_edge_kernel<false><<<(NV * 8 + 255) / 256, 256, 0, stream>>>(
            PXg, PCg, PXh, PAh, idx_g, eag, idx_h, eah,
            c2v_s, a2v_s, ea_c2v, ea_a2v,
            off_g, deg_g, off_h, deg_h, gv_W1, hv_W1, Ag, Ah, NV);
    }

    // variable-node MLP -> PFga (channel-parallel; f_v folded into ga partial)
    fv_node_kernel<<<(NV * 32 + 255) / 256, 256, 0, stream>>>(
        x_v, Ag, Ah, deg_g, deg_h,
        fv_W1, fv_b1, Mg, bgv, Mh, bhv, Nfv, bfv, PFga, NV);

    // cut-node edge aggregation (64 lanes/node)
    if (sorted) {
        ga_edge_kernel<true><<<(NA * 64 + 255) / 256, 256, 0, stream>>>(
            PXga, PFga, idx_a, eaa, a2v_t, ea_a2v,
            off_a, deg_a, ga_W1, Aga, NA);
    } else {
        ga_edge_kernel<false><<<(NA * 64 + 255) / 256, 256, 0, stream>>>(
            PXga, PFga, idx_a, eaa, a2v_t, ea_a2v,
            off_a, deg_a, ga_W1, Aga, NA);
    }

    // cut-node MLP -> output (channel-parallel)
    fa_node_kernel<<<(NA * 32 + 255) / 256, 256, 0, stream>>>(
        x_a, Aga, deg_a,
        fa_W1, fa_b1, fa_W2, fa_b2, Mga, bgav, (float*)d_out, NA);
}